// Round 6
// baseline (852.155 us; speedup 1.0000x reference)
//
#include <hip/hip_runtime.h>
#include <math.h>

// Problem constants
#define D_MODEL 512
#define NHEAD   8
#define DH      64
#define D_FF    2048
#define BATCH   16
#define SMAX    512
#define NTOK    (BATCH*SMAX)   // 8192
#define NLAYER  4

constexpr int MODE_QK   = 1;  // C cols 0..511 -> q rows, 512..1023 -> k rows [bh][s][64]
constexpr int MODE_VT   = 2;  // C[m=feature][n=token] -> vt [bh][d][s], bias along m
constexpr int MODE_RELU = 3;  // Cb = bf16(relu(A*B^T + bias)), row-major
constexpr int MODE_PART = 4;  // Cb[z] = bf16(A*B^T) partial over K-chunk z

typedef __attribute__((ext_vector_type(8))) __bf16 bf16x8;
typedef __attribute__((ext_vector_type(4))) float  f32x4;

__device__ __forceinline__ unsigned short f2bf(float f) {
  union { float f; unsigned u; } v; v.f = f;
  unsigned r = v.u + 0x7FFFu + ((v.u >> 16) & 1u);   // RNE
  return (unsigned short)(r >> 16);
}
__device__ __forceinline__ float bf2f(unsigned short u) {
  union { unsigned u; float f; } v; v.u = ((unsigned)u) << 16; return v.f;
}

__device__ __forceinline__ void gl_lds16(const unsigned short* g, unsigned short* l) {
  __builtin_amdgcn_global_load_lds(
      (const __attribute__((address_space(1))) unsigned int*)g,
      (__attribute__((address_space(3)))       unsigned int*)l, 16, 0, 0);
}

// ---------------------------------------------------------------------------
// bf16 MFMA GEMM, double-buffered K-loop, 256 threads = 4 waves (2x2),
// 128x128 tile, BK=32, 4x4 16x16x32 frags/wave (round-4 config).
// Epilogue: wave-private LDS bounce -> fully coalesced 16B/lane stores.
// ---------------------------------------------------------------------------
template<int MODE>
__global__ __launch_bounds__(256)
void gemm_mfma(const unsigned short* __restrict__ A,
               const unsigned short* __restrict__ Bw,
               const float* __restrict__ bias,
               unsigned short* __restrict__ Cb,
               unsigned short* __restrict__ qd, unsigned short* __restrict__ kd,
               int K, int CK, int N)
{
  __shared__ __attribute__((aligned(16))) unsigned short As[2][128*32];
  __shared__ __attribute__((aligned(16))) unsigned short Bs[2][128*32];
  const int tid  = threadIdx.x;
  const int m0   = blockIdx.y * 128, n0 = blockIdx.x * 128;
  const int lane = tid & 63;
  const int w    = tid >> 6;
  const int wm   = (w & 1) * 64;
  const int wn   = (w >> 1) * 64;
  const int l15  = lane & 15, quad = lane >> 4;
  const int kz   = (MODE == MODE_PART) ? blockIdx.z : 0;

  f32x4 acc[4][4] = {};

  const int sr = tid >> 2;            // 0..63
  const int sk = (tid & 3) * 8;
  const unsigned short* Ag = A  + (long)(m0 + sr) * K + kz*CK + sk;
  const unsigned short* Bg = Bw + (long)(n0 + sr) * K + kz*CK + sk;
  const long rowskip = (long)64 * K;
  const int t8 = tid * 8;

  // prologue: stage k0=0 into buffer 0
  gl_lds16(Ag,           &As[0][t8]);
  gl_lds16(Ag + rowskip, &As[0][2048 + t8]);
  gl_lds16(Bg,           &Bs[0][t8]);
  gl_lds16(Bg + rowskip, &Bs[0][2048 + t8]);

  for (int k0 = 0; k0 < CK; k0 += 32) {
    const int cur = (k0 >> 5) & 1;
    __syncthreads();              // buf[cur] ready; buf[cur^1] free
    if (k0 + 32 < CK) {
      Ag += 32; Bg += 32;
      gl_lds16(Ag,           &As[cur^1][t8]);
      gl_lds16(Ag + rowskip, &As[cur^1][2048 + t8]);
      gl_lds16(Bg,           &Bs[cur^1][t8]);
      gl_lds16(Bg + rowskip, &Bs[cur^1][2048 + t8]);
    }
    bf16x8 af[4], bfv[4];
#pragma unroll
    for (int i = 0; i < 4; i++)
      af[i] = *(const bf16x8*)&As[cur][(wm + i*16 + l15)*32 + quad*8];
#pragma unroll
    for (int j = 0; j < 4; j++)
      bfv[j] = *(const bf16x8*)&Bs[cur][(wn + j*16 + l15)*32 + quad*8];
#pragma unroll
    for (int i = 0; i < 4; i++)
#pragma unroll
      for (int j = 0; j < 4; j++)
        acc[i][j] = __builtin_amdgcn_mfma_f32_16x16x32_bf16(af[i], bfv[j], acc[i][j], 0, 0, 0);
  }

  // ---- epilogue: LDS bounce, coalesced stores ----
  __syncthreads();   // everyone done with As/Bs; repurpose as bounce buffers
  unsigned short* epi = ((w >> 1) ? &Bs[0][0] : &As[0][0]) + (w & 1) * 2048;
  // region per wave: 16 rows x stride 72 (1152 ushorts <= 2048)

  const int rr = lane >> 2, ch = lane & 3;
#pragma unroll
  for (int i = 0; i < 4; i++) {
    // write phase: rows quad*4+r, cols j*16+l15
    float rbv[4];
    if (MODE == MODE_VT) {
#pragma unroll
      for (int r = 0; r < 4; r++) rbv[r] = bias[m0 + wm + i*16 + quad*4 + r];
    }
#pragma unroll
    for (int j = 0; j < 4; j++) {
      float cbv = 0.f;
      if (MODE == MODE_QK || MODE == MODE_RELU) cbv = bias[n0 + wn + j*16 + l15];
#pragma unroll
      for (int r = 0; r < 4; r++) {
        float v = acc[i][j][r];
        if (MODE == MODE_QK)   v += cbv;
        if (MODE == MODE_RELU) v = fmaxf(v + cbv, 0.f);
        if (MODE == MODE_VT)   v += rbv[r];
        epi[(quad*4 + r)*72 + j*16 + l15] = f2bf(v);
      }
    }
    asm volatile("s_waitcnt lgkmcnt(0)" ::: "memory");

    // read phase: lane -> row rr, col chunk ch*16, 2 x b128, 16B stores
    const int mrow = m0 + wm + i*16 + rr;
#pragma unroll
    for (int c = 0; c < 2; c++) {
      bf16x8 val = *(const bf16x8*)&epi[rr*72 + ch*16 + c*8];
      if (MODE == MODE_RELU) {
        *(bf16x8*)&Cb[(long)mrow*N + n0 + wn + ch*16 + c*8] = val;
      } else if (MODE == MODE_PART) {
        *(bf16x8*)&Cb[((long)kz*NTOK + mrow)*N + n0 + wn + ch*16 + c*8] = val;
      } else if (MODE == MODE_QK) {
        const int nb    = n0 + wn;
        const int which = nb >> 9;
        const int head  = (nb >> 6) & 7;
        const int col   = ch*16 + c*8;
        unsigned short* dst = which ? kd : qd;
        const int bh = (mrow >> 9)*8 + head;
        *(bf16x8*)&dst[((long)(bh*512 + (mrow & 511)))*64 + col] = val;
      } else {  // MODE_VT: mrow = feature, token = n0+wn+...
        const int head = mrow >> 6, d = mrow & 63;
        const int tok  = n0 + wn + ch*16 + c*8;
        const int b    = tok >> 9;
        *(bf16x8*)&Cb[((long)((b*8 + head)*64 + d))*512 + (tok & 511)] = val;
      }
    }
    asm volatile("s_waitcnt lgkmcnt(0)" ::: "memory");  // region reuse next phase
  }
}

// ---------------------------------------------------------------------------
// Fused split-K reduce + bias + residual + LayerNorm.
// ---------------------------------------------------------------------------
template<int KS>
__global__ __launch_bounds__(128)
void reduce_ln(const unsigned short* __restrict__ part,
               const float* __restrict__ bias,
               const float* __restrict__ g, const float* __restrict__ bb,
               float* __restrict__ h, unsigned short* __restrict__ hb)
{
  const int row = blockIdx.x, tid = threadIdx.x;
  float4 x  = ((const float4*)(h + (long)row*512))[tid];
  float4 bs = ((const float4*)bias)[tid];
  float v0 = x.x + bs.x, v1 = x.y + bs.y, v2 = x.z + bs.z, v3 = x.w + bs.w;
#pragma unroll
  for (int z = 0; z < KS; z++) {
    ushort4 p = ((const ushort4*)(part + ((long)z*NTOK + row)*512))[tid];
    v0 += bf2f(p.x); v1 += bf2f(p.y); v2 += bf2f(p.z); v3 += bf2f(p.w);
  }
  float s  = v0 + v1 + v2 + v3;
  float s2 = v0*v0 + v1*v1 + v2*v2 + v3*v3;
#pragma unroll
  for (int off = 1; off < 64; off <<= 1) {
    s  += __shfl_xor(s, off);
    s2 += __shfl_xor(s2, off);
  }
  __shared__ float rb[4];
  if ((tid & 63) == 0) { rb[(tid>>6)*2] = s; rb[(tid>>6)*2+1] = s2; }
  __syncthreads();
  s = rb[0] + rb[2]; s2 = rb[1] + rb[3];
  const float mean = s * (1.f/512.f);
  const float var  = fmaxf(s2 * (1.f/512.f) - mean*mean, 0.f);
  const float rstd = rsqrtf(var + 1e-5f);
  const int e = tid*4;
  float4 o;
  o.x = (v0-mean)*rstd*g[e+0] + bb[e+0];
  o.y = (v1-mean)*rstd*g[e+1] + bb[e+1];
  o.z = (v2-mean)*rstd*g[e+2] + bb[e+2];
  o.w = (v3-mean)*rstd*g[e+3] + bb[e+3];
  ((float4*)(h + (long)row*512))[tid] = o;
  ushort4 ob;
  ob.x = f2bf(o.x); ob.y = f2bf(o.y); ob.z = f2bf(o.z); ob.w = f2bf(o.w);
  ((ushort4*)(hb + (long)row*512))[tid] = ob;
}

// ---------------------------------------------------------------------------
// MFMA flash attention, double-buffered staging from row-major K [bh][s][64]
// and VT [bh][d][s]. LDS tiles in bank-conflict-free half layouts.
// ---------------------------------------------------------------------------
__global__ __launch_bounds__(256)
void attn_mfma(const unsigned short* __restrict__ qg,
               const unsigned short* __restrict__ kb,
               const unsigned short* __restrict__ vtb,
               const int* __restrict__ lens,
               unsigned short* __restrict__ ctxb)
{
  __shared__ __attribute__((aligned(16))) unsigned short Ks[2][64*32*2];
  __shared__ __attribute__((aligned(16))) unsigned short Vts[2][64*32*2];
  __shared__ __attribute__((aligned(16))) unsigned short Ps[4*16*72];
  const int qt = blockIdx.x, hh = blockIdx.y, b = blockIdx.z;
  const int bh = b*8 + hh;
  const int tid = threadIdx.x;
  const int w = tid >> 6, lane = tid & 63, l15 = lane & 15, quad = lane >> 4;
  const int len = lens[b];
  const int t8 = tid * 8;

  // staging thread mapping
  const int srow = tid >> 2;          // key-row (K) or d-row (VT), 0..63
  const int s8   = (tid & 3) * 8;     // 8-elem chunk within 32-half
  // K: [bh][s][64]; tile kt rows kt*64..+63; half dh covers d 32*dh..+31
  const unsigned short* Kbase = kb  + ((long)(bh*512 + srow))*64 + s8;
  // VT: [bh][d][512]; tile kt cols kt*64..+63; half kh2 covers keys 32*kh2..+31
  const unsigned short* Vbase = vtb + ((long)(bh*64 + srow))*512 + s8;

  const unsigned short* qrow = qg + ((long)(bh*512 + qt*64 + w*16 + l15))*64;
  const bf16x8 qf0 = *(const bf16x8*)(qrow + quad*8);
  const bf16x8 qf1 = *(const bf16x8*)(qrow + 32 + quad*8);

  f32x4 O[4] = {};
  float mrow[4] = {-1e30f,-1e30f,-1e30f,-1e30f};
  float lrow[4] = {0.f,0.f,0.f,0.f};
  unsigned short* Pw = &Ps[w*16*72];
  const int ntiles = (len + 63) >> 6;

  // prologue stage tile 0 -> buf 0
  {
    gl_lds16(Kbase,                  &Ks[0][t8]);          // dh=0
    gl_lds16(Kbase + 32,             &Ks[0][2048 + t8]);   // dh=1
    gl_lds16(Vbase,                  &Vts[0][t8]);         // kh2=0
    gl_lds16(Vbase + 32,             &Vts[0][2048 + t8]);  // kh2=1
  }

  for (int kt = 0; kt < ntiles; kt++) {
    const int cur = kt & 1;
    __syncthreads();              // buf[cur] loads complete; buf[cur^1] free
    if (kt + 1 < ntiles) {
      const unsigned short* Kg = Kbase + (long)(kt+1)*64*64;  // 64 rows of 64
      const unsigned short* Vg = Vbase + (long)(kt+1)*64;     // 64 cols
      gl_lds16(Kg,      &Ks[cur^1][t8]);
      gl_lds16(Kg + 32, &Ks[cur^1][2048 + t8]);
      gl_lds16(Vg,      &Vts[cur^1][t8]);
      gl_lds16(Vg + 32, &Vts[cur^1][2048 + t8]);
    }

    // S = Q K^T : per wave 16q x 64k, C-layout (row=q=quad*4+r, col=k=l15)
    f32x4 sc[4];
#pragma unroll
    for (int ks = 0; ks < 4; ks++) {
      bf16x8 kf0 = *(const bf16x8*)&Ks[cur][       (ks*16 + l15)*32 + quad*8];
      bf16x8 kf1 = *(const bf16x8*)&Ks[cur][2048 + (ks*16 + l15)*32 + quad*8];
      f32x4 z = {};
      z = __builtin_amdgcn_mfma_f32_16x16x32_bf16(qf0, kf0, z, 0, 0, 0);
      sc[ks] = __builtin_amdgcn_mfma_f32_16x16x32_bf16(qf1, kf1, z, 0, 0, 0);
    }

#pragma unroll
    for (int ks = 0; ks < 4; ks++) {
      const bool valid = (kt*64 + ks*16 + l15) < len;
#pragma unroll
      for (int r = 0; r < 4; r++)
        sc[ks][r] = valid ? sc[ks][r]*0.125f : -1e30f;
    }

    float pv[4][4];
#pragma unroll
    for (int r = 0; r < 4; r++) {
      float mx = fmaxf(fmaxf(sc[0][r], sc[1][r]), fmaxf(sc[2][r], sc[3][r]));
      mx = fmaxf(mx, __shfl_xor(mx, 1));
      mx = fmaxf(mx, __shfl_xor(mx, 2));
      mx = fmaxf(mx, __shfl_xor(mx, 4));
      mx = fmaxf(mx, __shfl_xor(mx, 8));
      const float newm  = fmaxf(mrow[r], mx);
      const float alpha = __expf(mrow[r] - newm);
      float ps = 0.f;
#pragma unroll
      for (int ks = 0; ks < 4; ks++) { pv[ks][r] = __expf(sc[ks][r] - newm); ps += pv[ks][r]; }
      ps += __shfl_xor(ps, 1); ps += __shfl_xor(ps, 2);
      ps += __shfl_xor(ps, 4); ps += __shfl_xor(ps, 8);
      lrow[r] = lrow[r]*alpha + ps;
      mrow[r] = newm;
#pragma unroll
      for (int d = 0; d < 4; d++) O[d][r] *= alpha;
    }

    // P: C-layout -> A-layout via wave-private LDS
#pragma unroll
    for (int ks = 0; ks < 4; ks++)
#pragma unroll
      for (int r = 0; r < 4; r++)
        Pw[(quad*4 + r)*72 + ks*16 + l15] = f2bf(pv[ks][r]);
    asm volatile("s_waitcnt lgkmcnt(0)" ::: "memory");

    const bf16x8 pa0 = *(const bf16x8*)&Pw[l15*72 + quad*8];
    const bf16x8 pa1 = *(const bf16x8*)&Pw[l15*72 + 32 + quad*8];
#pragma unroll
    for (int d = 0; d < 4; d++) {
      bf16x8 vf0 = *(const bf16x8*)&Vts[cur][       (d*16 + l15)*32 + quad*8];
      bf16x8 vf1 = *(const bf16x8*)&Vts[cur][2048 + (d*16 + l15)*32 + quad*8];
      O[d] = __builtin_amdgcn_mfma_f32_16x16x32_bf16(pa0, vf0, O[d], 0, 0, 0);
      O[d] = __builtin_amdgcn_mfma_f32_16x16x32_bf16(pa1, vf1, O[d], 0, 0, 0);
    }
  }

  // ctx write via wave-private LDS bounce -> coalesced 16B stores
  asm volatile("s_waitcnt lgkmcnt(0)" ::: "memory");
#pragma unroll
  for (int r = 0; r < 4; r++) {
    const float inv = 1.f / lrow[r];
#pragma unroll
    for (int d = 0; d < 4; d++)
      Pw[(quad*4 + r)*72 + d*16 + l15] = f2bf(O[d][r] * inv);
  }
  asm volatile("s_waitcnt lgkmcnt(0)" ::: "memory");
  {
    const int rr = lane >> 2, ch = lane & 3;
    const long row = (long)(b*512 + qt*64 + w*16 + rr)*512 + hh*64;
    bf16x8 v0 = *(const bf16x8*)&Pw[rr*72 + ch*16 + 0];
    bf16x8 v1 = *(const bf16x8*)&Pw[rr*72 + ch*16 + 8];
    *(bf16x8*)&ctxb[row + ch*16 + 0] = v0;
    *(bf16x8*)&ctxb[row + ch*16 + 8] = v1;
  }
}

// ---------------------------------------------------------------------------
// fp32 embedding GEMM (K=80): h = x*We^T + be + posenc; writes fp32 + bf16.
// ---------------------------------------------------------------------------
__global__ __launch_bounds__(256)
void gemm_embed(const float* __restrict__ A, const float* __restrict__ Bm,
                const float* __restrict__ bias, float* __restrict__ C,
                unsigned short* __restrict__ Cb, int K, int N)
{
  __shared__ float As[8][132];
  __shared__ float Bs[8][68];
  const int tid = threadIdx.x;
  const int m0 = blockIdx.y * 128;
  const int n0 = blockIdx.x * 64;
  const int tx = tid & 15, ty = tid >> 4;
  const int a_k = tid & 7, a_m = tid >> 3;

  float acc[8][4] = {};
  const float* Ag = A  + (long)(m0 + a_m) * K + a_k;
  const float* Bg = Bm + (long)(n0 + a_m) * K + a_k;

  for (int k0 = 0; k0 < K; k0 += 8) {
#pragma unroll
    for (int i = 0; i < 4; i++)
      As[a_k][a_m + 32*i] = Ag[k0 + (long)32*i*K];
#pragma unroll
    for (int i = 0; i < 2; i++)
      Bs[a_k][a_m + 32*i] = Bg[k0 + (long)32*i*K];
    __syncthreads();
#pragma unroll
    for (int kk = 0; kk < 8; kk++) {
      float a[8], bv[4];
#pragma unroll
      for (int r = 0; r < 8; r++) a[r] = As[kk][ty*8 + r];
#pragma unroll
      for (int c = 0; c < 4; c++) bv[c] = Bs[kk][tx*4 + c];
#pragma unroll
      for (int r = 0; r < 8; r++)
#pragma unroll
        for (int c = 0; c < 4; c++)
          acc[r][c] += a[r] * bv[c];
    }
    __syncthreads();
  }

  const int n_base = n0 + tx*4;
#pragma unroll
  for (int r = 0; r < 8; r++) {
    int m = m0 + ty*8 + r;
    int s = m & 511;
    float4 v4; float* vp = &v4.x;
#pragma unroll
    for (int c = 0; c < 4; c++) {
      int e = n_base + c;
      float dv  = __expf((float)(e & ~1) * (-9.210340371976184f / 512.0f));
      float ang = (float)s * dv;
      vp[c] = acc[r][c] + bias[e] + ((e & 1) ? cosf(ang) : sinf(ang));
    }
    *(float4*)(C + (long)m*N + n_base) = v4;
    ushort4 ob;
    ob.x = f2bf(v4.x); ob.y = f2bf(v4.y); ob.z = f2bf(v4.z); ob.w = f2bf(v4.w);
    *(ushort4*)(Cb + (long)m*N + n_base) = ob;
  }
}

// fp32 -> bf16 cast (weights)
__global__ __launch_bounds__(256)
void cvt_kernel(const float* __restrict__ in, unsigned short* __restrict__ out, int n4)
{
  int i = blockIdx.x*256 + threadIdx.x;
  if (i < n4) {
    float4 v = ((const float4*)in)[i];
    ushort4 o;
    o.x = f2bf(v.x); o.y = f2bf(v.y); o.z = f2bf(v.z); o.w = f2bf(v.w);
    ((ushort4*)out)[i] = o;
  }
}

__global__ __launch_bounds__(256)
void out_init(float* __restrict__ out, const int* __restrict__ lens)
{
  int i = blockIdx.x*256 + threadIdx.x;
  if (i < 8192) out[i] = 0.f;
  else if (i < 8192 + 16) out[i] = (float)lens[i - 8192];
}

__global__ __launch_bounds__(256)
void pool_kernel(const float* __restrict__ h, const int* __restrict__ lens,
                 float* __restrict__ out)
{
  const int b = blockIdx.y;
  const int s0 = blockIdx.x * 64;
  const int len = lens[b];
  if (s0 >= len) return;
  const int send = min(s0 + 64, len);
  const int tid = threadIdx.x;
  float acc0 = 0.f, acc1 = 0.f;
  for (int s = s0; s < send; s++) {
    const float* row = h + (long)(b*512 + s)*512;
    acc0 += row[tid];
    acc1 += row[tid + 256];
  }
  const float inv = 1.0f / (float)len;
  atomicAdd(out + b*512 + tid,       acc0 * inv);
  atomicAdd(out + b*512 + tid + 256, acc1 * inv);
}

// ---------------------------------------------------------------------------
extern "C" void kernel_launch(void* const* d_in, const int* in_sizes, int n_in,
                              void* d_out, int out_size, void* d_ws, size_t ws_size,
                              hipStream_t stream)
{
  const float* x    = (const float*)d_in[0];
  const int*   lens = (const int*)  d_in[1];
  const float* We   = (const float*)d_in[2];
  const float* be   = (const float*)d_in[3];
  const float* Wqkv = (const float*)d_in[4];
  const float* bqkv = (const float*)d_in[5];
  const float* Wo   = (const float*)d_in[6];
  const float* bo   = (const float*)d_in[7];
  const float* ln1g = (const float*)d_in[8];
  const float* ln1b = (const float*)d_in[9];
  const float* W1   = (const float*)d_in[10];
  const float* b1   = (const float*)d_in[11];
  const float* W2   = (const float*)d_in[12];
  const float* b2   = (const float*)d_in[13];
  const float* ln2g = (const float*)d_in[14];
  const float* ln2b = (const float*)d_in[15];
  float* out = (float*)d_out;

  // Workspace layout
  const long TOK_D = (long)NTOK * D_MODEL;              // 4,194,304
  float* ws  = (float*)d_ws;
  float* h   = ws;                                      // fp32 [8192,512]
  unsigned short* us    = (unsigned short*)(ws + 1*TOK_D);
  unsigned short* h_b   = us;                           // bf16 [8192,512]
  unsigned short* ctx_b = us + 1*TOK_D;
  unsigned short* q_b   = us + 2*TOK_D;                 // [bh][s][64]
  unsigned short* k_b   = us + 3*TOK_D;                 // [bh][s][64]
  unsigned short* vt_b  = us + 4*TOK_D;                 // [bh][d][s]
  unsigned short* ff_b  = us + 5*TOK_D;                 // bf16 [8192,2048]
  unsigned short* wq_b  = us + 9*TOK_D;
  unsigned short* wo_b  = wq_b + (long)NLAYER*3*D_MODEL*D_MODEL;
  unsigned short* w1_b  = wo_b + (long)NLAYER*D_MODEL*D_MODEL;
  unsigned short* w2_b  = w1_b + (long)NLAYER*D_FF*D_MODEL;
  unsigned short* part  = w2_b + (long)NLAYER*D_MODEL*D_FF;  // [<=4][8192][512]

  const dim3 blk(256);

  // 0) weight casts fp32->bf16
  {
    int n4;
    n4 = NLAYER*3*D_MODEL*D_MODEL/4;
    cvt_kernel<<<dim3((n4+255)/256), blk, 0, stream>>>(Wqkv, wq_b, n4);
    n4 = NLAYER*D_MODEL*D_MODEL/4;
    cvt_kernel<<<dim3((n4+255)/256), blk, 0, stream>>>(Wo, wo_b, n4);
    n4 = NLAYER*D_FF*D_MODEL/4;
    cvt_kernel<<<dim3((n4+255)/256), blk, 0, stream>>>(W1, w1_b, n4);
    n4 = NLAYER*D_MODEL*D_FF/4;
    cvt_kernel<<<dim3((n4+255)/256), blk, 0, stream>>>(W2, w2_b, n4);
  }

  // 1) embedding + posenc (fp32), writes h + h_b
  gemm_embed<<<dim3(D_MODEL/64, NTOK/128), blk, 0, stream>>>(
      x, We, be, h, h_b, 80, D_MODEL);

  for (int l = 0; l < NLAYER; l++) {
    const unsigned short* wq_l = wq_b + (long)l * 3*D_MODEL * D_MODEL;
    const unsigned short* wo_l = wo_b + (long)l * D_MODEL * D_MODEL;
    const unsigned short* w1_l = w1_b + (long)l * D_FF * D_MODEL;
    const unsigned short* w2_l = w2_b + (long)l * D_MODEL * D_FF;
    const float* bqkv_l = bqkv + (long)l * 3*D_MODEL;
    const float* bo_l   = bo   + (long)l * D_MODEL;
    const float* b1_l   = b1   + (long)l * D_FF;
    const float* b2_l   = b2   + (long)l * D_MODEL;

    // q,k = h*Wqk^T + b  -> row-major [bh][s][64]   (512 blocks)
    gemm_mfma<MODE_QK><<<dim3(2*D_MODEL/128, NTOK/128), blk, 0, stream>>>(
        h_b, wq_l, bqkv_l, nullptr, q_b, k_b, D_MODEL, D_MODEL, 2*D_MODEL);

    // v^T = Wv*h^T + bv (bias along features) -> [bh][d][s]   (256 blocks)
    gemm_mfma<MODE_VT><<<dim3(NTOK/128, D_MODEL/128), blk, 0, stream>>>(
        wq_l + (long)2*D_MODEL*D_MODEL, h_b, bqkv_l + 2*D_MODEL, vt_b,
        nullptr, nullptr, D_MODEL, D_MODEL, NTOK);

    // attention -> ctx_b (bf16 [B,S,512])  (1024 blocks)
    attn_mfma<<<dim3(SMAX/64, NHEAD, BATCH), blk, 0, stream>>>(
        q_b, k_b, vt_b, lens, ctx_b);

    // Wo partials: split-K x2 (CK=256), then fused reduce+resid+LN1
    gemm_mfma<MODE_PART><<<dim3(D_MODEL/128, NTOK/128, 2), blk, 0, stream>>>(
        ctx_b, wo_l, nullptr, part, nullptr, nullptr, D_MODEL, D_MODEL/2, D_MODEL);
    reduce_ln<2><<<dim3(NTOK), dim3(128), 0, stream>>>(
        part, bo_l, ln1g + l*D_MODEL, ln1b + l*D_MODEL, h, h_b);

    // ff_b = bf16(relu(h*W1^T + b1))  (1024 blocks)
    gemm_mfma<MODE_RELU><<<dim3(D_FF/128, NTOK/128), blk, 0, stream>>>(
        h_b, w1_l, b1_l, ff_b, nullptr, nullptr, D_MODEL, D_MODEL, D_FF);

    // FF2 partials: split-K x4 (CK=512), then fused reduce+resid+LN2
    gemm_mfma<MODE_PART><<<dim3(D_MODEL/128, NTOK/128, 4), blk, 0, stream>>>(
        ff_b, w2_l, nullptr, part, nullptr, nullptr, D_FF, D_FF/4, D_MODEL);
    reduce_ln<4><<<dim3(NTOK), dim3(128), 0, stream>>>(
        part, b2_l, ln2g + l*D_MODEL, ln2b + l*D_MODEL, h, h_b);
  }

  // 3) masked mean pool + lens output
  out_init<<<dim3((8192 + 16 + 255) / 256), blk, 0, stream>>>(out, lens);
  pool_kernel<<<dim3(SMAX/64, BATCH), blk, 0, stream>>>(h, lens, out);
}

// Round 7
// 841.585 us; speedup vs baseline: 1.0126x; 1.0126x over previous
//
#include <hip/hip_runtime.h>
#include <math.h>

// Problem constants
#define D_MODEL 512
#define NHEAD   8
#define DH      64
#define D_FF    2048
#define BATCH   16
#define SMAX    512
#define NTOK    (BATCH*SMAX)   // 8192
#define NLAYER  4

constexpr int MODE_QK   = 1;  // C cols 0..511 -> q rows, 512..1023 -> k rows [bh][s][64]
constexpr int MODE_VT   = 2;  // C[m=feature][n=token] -> vt [bh][d][s], bias along m
constexpr int MODE_RELU = 3;  // Cb = bf16(relu(A*B^T + bias)), row-major
constexpr int MODE_PART = 4;  // Cb[z] = bf16(A*B^T) partial over K-chunk z

typedef __attribute__((ext_vector_type(8))) __bf16 bf16x8;
typedef __attribute__((ext_vector_type(4))) float  f32x4;

__device__ __forceinline__ unsigned short f2bf(float f) {
  union { float f; unsigned u; } v; v.f = f;
  unsigned r = v.u + 0x7FFFu + ((v.u >> 16) & 1u);   // RNE
  return (unsigned short)(r >> 16);
}
__device__ __forceinline__ float bf2f(unsigned short u) {
  union { unsigned u; float f; } v; v.u = ((unsigned)u) << 16; return v.f;
}

__device__ __forceinline__ void gl_lds16(const unsigned short* g, unsigned short* l) {
  __builtin_amdgcn_global_load_lds(
      (const __attribute__((address_space(1))) unsigned int*)g,
      (__attribute__((address_space(3)))       unsigned int*)l, 16, 0, 0);
}

// ---------------------------------------------------------------------------
// bf16 MFMA GEMM, 3-stage pipelined K-loop with raw vmcnt(4)+s_barrier.
// 256 threads = 4 waves (2x2), 128x128 tile, BK=32, 4x4 16x16x32 frags/wave.
// Each wave issues 4 global_load_lds per tile; at the barrier we wait only
// for the CURRENT tile (vmcnt(4) leaves the next prefetch in flight), so each
// load gets ~2 compute iterations (~800 cyc) to cover ~900 cyc HBM latency.
// Epilogue: wave-private LDS bounce -> dense 128B-line stores (no RMW).
// ---------------------------------------------------------------------------
template<int MODE>
__global__ __launch_bounds__(256)
void gemm_mfma(const unsigned short* __restrict__ A,
               const unsigned short* __restrict__ Bw,
               const float* __restrict__ bias,
               unsigned short* __restrict__ Cb,
               unsigned short* __restrict__ qd, unsigned short* __restrict__ kd,
               int K, int CK, int N)
{
  __shared__ __attribute__((aligned(16))) unsigned short As[3][128*32];
  __shared__ __attribute__((aligned(16))) unsigned short Bs[3][128*32];
  const int tid  = threadIdx.x;
  const int m0   = blockIdx.y * 128, n0 = blockIdx.x * 128;
  const int lane = tid & 63;
  const int w    = tid >> 6;
  const int wm   = (w & 1) * 64;
  const int wn   = (w >> 1) * 64;
  const int l15  = lane & 15, quad = lane >> 4;
  const int kz   = (MODE == MODE_PART) ? blockIdx.z : 0;

  f32x4 acc[4][4] = {};

  const int sr = tid >> 2;            // 0..63
  const int sk = (tid & 3) * 8;
  const unsigned short* Ag = A  + (long)(m0 + sr) * K + kz*CK + sk;
  const unsigned short* Bg = Bw + (long)(n0 + sr) * K + kz*CK + sk;
  const long rowskip = (long)64 * K;
  const int t8 = tid * 8;
  const int niter = CK >> 5;

  auto stage = [&](int t, int bix) {
    const unsigned short* a_ = Ag + t*32;
    const unsigned short* b_ = Bg + t*32;
    gl_lds16(a_,           &As[bix][t8]);
    gl_lds16(a_ + rowskip, &As[bix][2048 + t8]);
    gl_lds16(b_,           &Bs[bix][t8]);
    gl_lds16(b_ + rowskip, &Bs[bix][2048 + t8]);
  };

  stage(0, 0);
  stage(1, 1);

  for (int it = 0; it < niter; ++it) {
    // wait for tile `it` only: 4 loads of tile it are the oldest; tile it+1's
    // 4 may stay in flight. Last iter: nothing newer -> vmcnt(0).
    if (it + 1 < niter)
      asm volatile("s_waitcnt vmcnt(4)\n\ts_barrier" ::: "memory");
    else
      asm volatile("s_waitcnt vmcnt(0)\n\ts_barrier" ::: "memory");
    if (it + 2 < niter) stage(it + 2, (it + 2) % 3);

    const int cur = it % 3;
    bf16x8 af[4], bfv[4];
#pragma unroll
    for (int i = 0; i < 4; i++)
      af[i] = *(const bf16x8*)&As[cur][(wm + i*16 + l15)*32 + quad*8];
#pragma unroll
    for (int j = 0; j < 4; j++)
      bfv[j] = *(const bf16x8*)&Bs[cur][(wn + j*16 + l15)*32 + quad*8];
#pragma unroll
    for (int i = 0; i < 4; i++)
#pragma unroll
      for (int j = 0; j < 4; j++)
        acc[i][j] = __builtin_amdgcn_mfma_f32_16x16x32_bf16(af[i], bfv[j], acc[i][j], 0, 0, 0);
  }

  // ---- epilogue: LDS bounce, dense 128B-line stores ----
  __syncthreads();   // all waves done with As/Bs; repurpose as bounce buffers
  unsigned short* epi = &As[0][0] + w * 1152;   // 16 rows x stride 72 per wave
  const int rr8 = lane >> 3, ch8 = lane & 7;

#pragma unroll
  for (int i = 0; i < 4; i++) {
    float rbv[4];
    if (MODE == MODE_VT) {
#pragma unroll
      for (int r = 0; r < 4; r++) rbv[r] = bias[m0 + wm + i*16 + quad*4 + r];
    }
#pragma unroll
    for (int j = 0; j < 4; j++) {
      float cbv = 0.f;
      if (MODE == MODE_QK || MODE == MODE_RELU) cbv = bias[n0 + wn + j*16 + l15];
#pragma unroll
      for (int r = 0; r < 4; r++) {
        float v = acc[i][j][r];
        if (MODE == MODE_QK)   v += cbv;
        if (MODE == MODE_RELU) v = fmaxf(v + cbv, 0.f);
        if (MODE == MODE_VT)   v += rbv[r];
        epi[(quad*4 + r)*72 + j*16 + l15] = f2bf(v);
      }
    }
    asm volatile("s_waitcnt lgkmcnt(0)" ::: "memory");

    // read+store: 8 lanes x 16B = 128B dense per store instruction
#pragma unroll
    for (int rs = 0; rs < 2; rs++) {
      const int row  = rs*8 + rr8;
      const int mrow = m0 + wm + i*16 + row;
      bf16x8 val = *(const bf16x8*)&epi[row*72 + ch8*8];
      if (MODE == MODE_RELU) {
        *(bf16x8*)&Cb[(long)mrow*N + n0 + wn + ch8*8] = val;
      } else if (MODE == MODE_PART) {
        *(bf16x8*)&Cb[((long)kz*NTOK + mrow)*N + n0 + wn + ch8*8] = val;
      } else if (MODE == MODE_QK) {
        const int nb    = n0 + wn;
        const int which = nb >> 9;
        const int head  = (nb >> 6) & 7;
        unsigned short* dst = which ? kd : qd;
        const int bh = (mrow >> 9)*8 + head;
        *(bf16x8*)&dst[((long)(bh*512 + (mrow & 511)))*64 + ch8*8] = val;
      } else {  // MODE_VT: mrow = feature, cols = tokens
        const int head = mrow >> 6, d = mrow & 63;
        const int tok  = n0 + wn + ch8*8;
        const int b    = tok >> 9;
        *(bf16x8*)&Cb[((long)((b*8 + head)*64 + d))*512 + (tok & 511)] = val;
      }
    }
  }
}

// ---------------------------------------------------------------------------
// Fused split-K reduce + bias + residual + LayerNorm.
// ---------------------------------------------------------------------------
template<int KS>
__global__ __launch_bounds__(128)
void reduce_ln(const unsigned short* __restrict__ part,
               const float* __restrict__ bias,
               const float* __restrict__ g, const float* __restrict__ bb,
               float* __restrict__ h, unsigned short* __restrict__ hb)
{
  const int row = blockIdx.x, tid = threadIdx.x;
  float4 x  = ((const float4*)(h + (long)row*512))[tid];
  float4 bs = ((const float4*)bias)[tid];
  float v0 = x.x + bs.x, v1 = x.y + bs.y, v2 = x.z + bs.z, v3 = x.w + bs.w;
#pragma unroll
  for (int z = 0; z < KS; z++) {
    ushort4 p = ((const ushort4*)(part + ((long)z*NTOK + row)*512))[tid];
    v0 += bf2f(p.x); v1 += bf2f(p.y); v2 += bf2f(p.z); v3 += bf2f(p.w);
  }
  float s  = v0 + v1 + v2 + v3;
  float s2 = v0*v0 + v1*v1 + v2*v2 + v3*v3;
#pragma unroll
  for (int off = 1; off < 64; off <<= 1) {
    s  += __shfl_xor(s, off);
    s2 += __shfl_xor(s2, off);
  }
  __shared__ float rb[4];
  if ((tid & 63) == 0) { rb[(tid>>6)*2] = s; rb[(tid>>6)*2+1] = s2; }
  __syncthreads();
  s = rb[0] + rb[2]; s2 = rb[1] + rb[3];
  const float mean = s * (1.f/512.f);
  const float var  = fmaxf(s2 * (1.f/512.f) - mean*mean, 0.f);
  const float rstd = rsqrtf(var + 1e-5f);
  const int e = tid*4;
  float4 o;
  o.x = (v0-mean)*rstd*g[e+0] + bb[e+0];
  o.y = (v1-mean)*rstd*g[e+1] + bb[e+1];
  o.z = (v2-mean)*rstd*g[e+2] + bb[e+2];
  o.w = (v3-mean)*rstd*g[e+3] + bb[e+3];
  ((float4*)(h + (long)row*512))[tid] = o;
  ushort4 ob;
  ob.x = f2bf(o.x); ob.y = f2bf(o.y); ob.z = f2bf(o.z); ob.w = f2bf(o.w);
  ((ushort4*)(hb + (long)row*512))[tid] = ob;
}

// ---------------------------------------------------------------------------
// MFMA flash attention, double-buffered staging from row-major K [bh][s][64]
// and VT [bh][d][s]. LDS tiles in bank-conflict-free half layouts.
// ---------------------------------------------------------------------------
__global__ __launch_bounds__(256)
void attn_mfma(const unsigned short* __restrict__ qg,
               const unsigned short* __restrict__ kb,
               const unsigned short* __restrict__ vtb,
               const int* __restrict__ lens,
               unsigned short* __restrict__ ctxb)
{
  __shared__ __attribute__((aligned(16))) unsigned short Ks[2][64*32*2];
  __shared__ __attribute__((aligned(16))) unsigned short Vts[2][64*32*2];
  __shared__ __attribute__((aligned(16))) unsigned short Ps[4*16*72];
  const int qt = blockIdx.x, hh = blockIdx.y, b = blockIdx.z;
  const int bh = b*8 + hh;
  const int tid = threadIdx.x;
  const int w = tid >> 6, lane = tid & 63, l15 = lane & 15, quad = lane >> 4;
  const int len = lens[b];
  const int t8 = tid * 8;

  const int srow = tid >> 2;
  const int s8   = (tid & 3) * 8;
  const unsigned short* Kbase = kb  + ((long)(bh*512 + srow))*64 + s8;
  const unsigned short* Vbase = vtb + ((long)(bh*64 + srow))*512 + s8;

  const unsigned short* qrow = qg + ((long)(bh*512 + qt*64 + w*16 + l15))*64;
  const bf16x8 qf0 = *(const bf16x8*)(qrow + quad*8);
  const bf16x8 qf1 = *(const bf16x8*)(qrow + 32 + quad*8);

  f32x4 O[4] = {};
  float mrow[4] = {-1e30f,-1e30f,-1e30f,-1e30f};
  float lrow[4] = {0.f,0.f,0.f,0.f};
  unsigned short* Pw = &Ps[w*16*72];
  const int ntiles = (len + 63) >> 6;

  // prologue stage tile 0 -> buf 0
  {
    gl_lds16(Kbase,      &Ks[0][t8]);
    gl_lds16(Kbase + 32, &Ks[0][2048 + t8]);
    gl_lds16(Vbase,      &Vts[0][t8]);
    gl_lds16(Vbase + 32, &Vts[0][2048 + t8]);
  }

  for (int kt = 0; kt < ntiles; kt++) {
    const int cur = kt & 1;
    __syncthreads();
    if (kt + 1 < ntiles) {
      const unsigned short* Kg = Kbase + (long)(kt+1)*64*64;
      const unsigned short* Vg = Vbase + (long)(kt+1)*64;
      gl_lds16(Kg,      &Ks[cur^1][t8]);
      gl_lds16(Kg + 32, &Ks[cur^1][2048 + t8]);
      gl_lds16(Vg,      &Vts[cur^1][t8]);
      gl_lds16(Vg + 32, &Vts[cur^1][2048 + t8]);
    }

    f32x4 sc[4];
#pragma unroll
    for (int ks = 0; ks < 4; ks++) {
      bf16x8 kf0 = *(const bf16x8*)&Ks[cur][       (ks*16 + l15)*32 + quad*8];
      bf16x8 kf1 = *(const bf16x8*)&Ks[cur][2048 + (ks*16 + l15)*32 + quad*8];
      f32x4 z = {};
      z = __builtin_amdgcn_mfma_f32_16x16x32_bf16(qf0, kf0, z, 0, 0, 0);
      sc[ks] = __builtin_amdgcn_mfma_f32_16x16x32_bf16(qf1, kf1, z, 0, 0, 0);
    }

#pragma unroll
    for (int ks = 0; ks < 4; ks++) {
      const bool valid = (kt*64 + ks*16 + l15) < len;
#pragma unroll
      for (int r = 0; r < 4; r++)
        sc[ks][r] = valid ? sc[ks][r]*0.125f : -1e30f;
    }

    float pv[4][4];
#pragma unroll
    for (int r = 0; r < 4; r++) {
      float mx = fmaxf(fmaxf(sc[0][r], sc[1][r]), fmaxf(sc[2][r], sc[3][r]));
      mx = fmaxf(mx, __shfl_xor(mx, 1));
      mx = fmaxf(mx, __shfl_xor(mx, 2));
      mx = fmaxf(mx, __shfl_xor(mx, 4));
      mx = fmaxf(mx, __shfl_xor(mx, 8));
      const float newm  = fmaxf(mrow[r], mx);
      const float alpha = __expf(mrow[r] - newm);
      float ps = 0.f;
#pragma unroll
      for (int ks = 0; ks < 4; ks++) { pv[ks][r] = __expf(sc[ks][r] - newm); ps += pv[ks][r]; }
      ps += __shfl_xor(ps, 1); ps += __shfl_xor(ps, 2);
      ps += __shfl_xor(ps, 4); ps += __shfl_xor(ps, 8);
      lrow[r] = lrow[r]*alpha + ps;
      mrow[r] = newm;
#pragma unroll
      for (int d = 0; d < 4; d++) O[d][r] *= alpha;
    }

#pragma unroll
    for (int ks = 0; ks < 4; ks++)
#pragma unroll
      for (int r = 0; r < 4; r++)
        Pw[(quad*4 + r)*72 + ks*16 + l15] = f2bf(pv[ks][r]);
    asm volatile("s_waitcnt lgkmcnt(0)" ::: "memory");

    const bf16x8 pa0 = *(const bf16x8*)&Pw[l15*72 + quad*8];
    const bf16x8 pa1 = *(const bf16x8*)&Pw[l15*72 + 32 + quad*8];
#pragma unroll
    for (int d = 0; d < 4; d++) {
      bf16x8 vf0 = *(const bf16x8*)&Vts[cur][       (d*16 + l15)*32 + quad*8];
      bf16x8 vf1 = *(const bf16x8*)&Vts[cur][2048 + (d*16 + l15)*32 + quad*8];
      O[d] = __builtin_amdgcn_mfma_f32_16x16x32_bf16(pa0, vf0, O[d], 0, 0, 0);
      O[d] = __builtin_amdgcn_mfma_f32_16x16x32_bf16(pa1, vf1, O[d], 0, 0, 0);
    }
  }

  // ctx write via wave-private LDS bounce -> dense 128B stores
#pragma unroll
  for (int r = 0; r < 4; r++) {
    const float inv = 1.f / lrow[r];
#pragma unroll
    for (int d = 0; d < 4; d++)
      Pw[(quad*4 + r)*72 + d*16 + l15] = f2bf(O[d][r] * inv);
  }
  asm volatile("s_waitcnt lgkmcnt(0)" ::: "memory");
  {
    const int rr8 = lane >> 3, ch8 = lane & 7;
#pragma unroll
    for (int rs = 0; rs < 2; rs++) {
      const int row = rs*8 + rr8;
      const long gaddr = (long)(b*512 + qt*64 + w*16 + row)*512 + hh*64 + ch8*8;
      *(bf16x8*)&ctxb[gaddr] = *(const bf16x8*)&Pw[row*72 + ch8*8];
    }
  }
}

// ---------------------------------------------------------------------------
// fp32 embedding GEMM (K=80): h = x*We^T + be + posenc; writes fp32 + bf16.
// ---------------------------------------------------------------------------
__global__ __launch_bounds__(256)
void gemm_embed(const float* __restrict__ A, const float* __restrict__ Bm,
                const float* __restrict__ bias, float* __restrict__ C,
                unsigned short* __restrict__ Cb, int K, int N)
{
  __shared__ float As[8][132];
  __shared__ float Bs[8][68];
  const int tid = threadIdx.x;
  const int m0 = blockIdx.y * 128;
  const int n0 = blockIdx.x * 64;
  const int tx = tid & 15, ty = tid >> 4;
  const int a_k = tid & 7, a_m = tid >> 3;

  float acc[8][4] = {};
  const float* Ag = A  + (long)(m0 + a_m) * K + a_k;
  const float* Bg = Bm + (long)(n0 + a_m) * K + a_k;

  for (int k0 = 0; k0 < K; k0 += 8) {
#pragma unroll
    for (int i = 0; i < 4; i++)
      As[a_k][a_m + 32*i] = Ag[k0 + (long)32*i*K];
#pragma unroll
    for (int i = 0; i < 2; i++)
      Bs[a_k][a_m + 32*i] = Bg[k0 + (long)32*i*K];
    __syncthreads();
#pragma unroll
    for (int kk = 0; kk < 8; kk++) {
      float a[8], bv[4];
#pragma unroll
      for (int r = 0; r < 8; r++) a[r] = As[kk][ty*8 + r];
#pragma unroll
      for (int c = 0; c < 4; c++) bv[c] = Bs[kk][tx*4 + c];
#pragma unroll
      for (int r = 0; r < 8; r++)
#pragma unroll
        for (int c = 0; c < 4; c++)
          acc[r][c] += a[r] * bv[c];
    }
    __syncthreads();
  }

  const int n_base = n0 + tx*4;
#pragma unroll
  for (int r = 0; r < 8; r++) {
    int m = m0 + ty*8 + r;
    int s = m & 511;
    float4 v4; float* vp = &v4.x;
#pragma unroll
    for (int c = 0; c < 4; c++) {
      int e = n_base + c;
      float dv  = __expf((float)(e & ~1) * (-9.210340371976184f / 512.0f));
      float ang = (float)s * dv;
      vp[c] = acc[r][c] + bias[e] + ((e & 1) ? cosf(ang) : sinf(ang));
    }
    *(float4*)(C + (long)m*N + n_base) = v4;
    ushort4 ob;
    ob.x = f2bf(v4.x); ob.y = f2bf(v4.y); ob.z = f2bf(v4.z); ob.w = f2bf(v4.w);
    *(ushort4*)(Cb + (long)m*N + n_base) = ob;
  }
}

// fp32 -> bf16 cast (weights)
__global__ __launch_bounds__(256)
void cvt_kernel(const float* __restrict__ in, unsigned short* __restrict__ out, int n4)
{
  int i = blockIdx.x*256 + threadIdx.x;
  if (i < n4) {
    float4 v = ((const float4*)in)[i];
    ushort4 o;
    o.x = f2bf(v.x); o.y = f2bf(v.y); o.z = f2bf(v.z); o.w = f2bf(v.w);
    ((ushort4*)out)[i] = o;
  }
}

__global__ __launch_bounds__(256)
void out_init(float* __restrict__ out, const int* __restrict__ lens)
{
  int i = blockIdx.x*256 + threadIdx.x;
  if (i < 8192) out[i] = 0.f;
  else if (i < 8192 + 16) out[i] = (float)lens[i - 8192];
}

__global__ __launch_bounds__(256)
void pool_kernel(const float* __restrict__ h, const int* __restrict__ lens,
                 float* __restrict__ out)
{
  const int b = blockIdx.y;
  const int s0 = blockIdx.x * 64;
  const int len = lens[b];
  if (s0 >= len) return;
  const int send = min(s0 + 64, len);
  const int tid = threadIdx.x;
  float acc0 = 0.f, acc1 = 0.f;
  for (int s = s0; s < send; s++) {
    const float* row = h + (long)(b*512 + s)*512;
    acc0 += row[tid];
    acc1 += row[tid + 256];
  }
  const float inv = 1.0f / (float)len;
  atomicAdd(out + b*512 + tid,       acc0 * inv);
  atomicAdd(out + b*512 + tid + 256, acc1 * inv);
}

// ---------------------------------------------------------------------------
extern "C" void kernel_launch(void* const* d_in, const int* in_sizes, int n_in,
                              void* d_out, int out_size, void* d_ws, size_t ws_size,
                              hipStream_t stream)
{
  const float* x    = (const float*)d_in[0];
  const int*   lens = (const int*)  d_in[1];
  const float* We   = (const float*)d_in[2];
  const float* be   = (const float*)d_in[3];
  const float* Wqkv = (const float*)d_in[4];
  const float* bqkv = (const float*)d_in[5];
  const float* Wo   = (const float*)d_in[6];
  const float* bo   = (const float*)d_in[7];
  const float* ln1g = (const float*)d_in[8];
  const float* ln1b = (const float*)d_in[9];
  const float* W1   = (const float*)d_in[10];
  const float* b1   = (const float*)d_in[11];
  const float* W2   = (const float*)d_in[12];
  const float* b2   = (const float*)d_in[13];
  const float* ln2g = (const float*)d_in[14];
  const float* ln2b = (const float*)d_in[15];
  float* out = (float*)d_out;

  // Workspace layout
  const long TOK_D = (long)NTOK * D_MODEL;              // 4,194,304
  float* ws  = (float*)d_ws;
  float* h   = ws;                                      // fp32 [8192,512]
  unsigned short* us    = (unsigned short*)(ws + 1*TOK_D);
  unsigned short* h_b   = us;                           // bf16 [8192,512]
  unsigned short* ctx_b = us + 1*TOK_D;
  unsigned short* q_b   = us + 2*TOK_D;                 // [bh][s][64]
  unsigned short* k_b   = us + 3*TOK_D;                 // [bh][s][64]
  unsigned short* vt_b  = us + 4*TOK_D;                 // [bh][d][s]
  unsigned short* ff_b  = us + 5*TOK_D;                 // bf16 [8192,2048]
  unsigned short* wq_b  = us + 9*TOK_D;
  unsigned short* wo_b  = wq_b + (long)NLAYER*3*D_MODEL*D_MODEL;
  unsigned short* w1_b  = wo_b + (long)NLAYER*D_MODEL*D_MODEL;
  unsigned short* w2_b  = w1_b + (long)NLAYER*D_FF*D_MODEL;
  unsigned short* part  = w2_b + (long)NLAYER*D_MODEL*D_FF;  // [<=4][8192][512]

  const dim3 blk(256);

  // 0) weight casts fp32->bf16
  {
    int n4;
    n4 = NLAYER*3*D_MODEL*D_MODEL/4;
    cvt_kernel<<<dim3((n4+255)/256), blk, 0, stream>>>(Wqkv, wq_b, n4);
    n4 = NLAYER*D_MODEL*D_MODEL/4;
    cvt_kernel<<<dim3((n4+255)/256), blk, 0, stream>>>(Wo, wo_b, n4);
    n4 = NLAYER*D_FF*D_MODEL/4;
    cvt_kernel<<<dim3((n4+255)/256), blk, 0, stream>>>(W1, w1_b, n4);
    n4 = NLAYER*D_MODEL*D_FF/4;
    cvt_kernel<<<dim3((n4+255)/256), blk, 0, stream>>>(W2, w2_b, n4);
  }

  // 1) embedding + posenc (fp32), writes h + h_b
  gemm_embed<<<dim3(D_MODEL/64, NTOK/128), blk, 0, stream>>>(
      x, We, be, h, h_b, 80, D_MODEL);

  for (int l = 0; l < NLAYER; l++) {
    const unsigned short* wq_l = wq_b + (long)l * 3*D_MODEL * D_MODEL;
    const unsigned short* wo_l = wo_b + (long)l * D_MODEL * D_MODEL;
    const unsigned short* w1_l = w1_b + (long)l * D_FF * D_MODEL;
    const unsigned short* w2_l = w2_b + (long)l * D_MODEL * D_FF;
    const float* bqkv_l = bqkv + (long)l * 3*D_MODEL;
    const float* bo_l   = bo   + (long)l * D_MODEL;
    const float* b1_l   = b1   + (long)l * D_FF;
    const float* b2_l   = b2   + (long)l * D_MODEL;

    // q,k = h*Wqk^T + b  -> row-major [bh][s][64]   (512 blocks)
    gemm_mfma<MODE_QK><<<dim3(2*D_MODEL/128, NTOK/128), blk, 0, stream>>>(
        h_b, wq_l, bqkv_l, nullptr, q_b, k_b, D_MODEL, D_MODEL, 2*D_MODEL);

    // v^T = Wv*h^T + bv (bias along features) -> [bh][d][s]   (256 blocks)
    gemm_mfma<MODE_VT><<<dim3(NTOK/128, D_MODEL/128), blk, 0, stream>>>(
        wq_l + (long)2*D_MODEL*D_MODEL, h_b, bqkv_l + 2*D_MODEL, vt_b,
        nullptr, nullptr, D_MODEL, D_MODEL, NTOK);

    // attention -> ctx_b (bf16 [B,S,512])  (1024 blocks)
    attn_mfma<<<dim3(SMAX/64, NHEAD, BATCH), blk, 0, stream>>>(
        q_b, k_b, vt_b, lens, ctx_b);

    // Wo partials: split-K x2 (CK=256), then fused reduce+resid+LN1
    gemm_mfma<MODE_PART><<<dim3(D_MODEL/128, NTOK/128, 2), blk, 0, stream>>>(
        ctx_b, wo_l, nullptr, part, nullptr, nullptr, D_MODEL, D_MODEL/2, D_MODEL);
    reduce_ln<2><<<dim3(NTOK), dim3(128), 0, stream>>>(
        part, bo_l, ln1g + l*D_MODEL, ln1b + l*D_MODEL, h, h_b);

    // ff_b = bf16(relu(h*W1^T + b1))  (1024 blocks)
    gemm_mfma<MODE_RELU><<<dim3(D_FF/128, NTOK/128), blk, 0, stream>>>(
        h_b, w1_l, b1_l, ff_b, nullptr, nullptr, D_MODEL, D_MODEL, D_FF);

    // FF2 partials: split-K x4 (CK=512), then fused reduce+resid+LN2
    gemm_mfma<MODE_PART><<<dim3(D_MODEL/128, NTOK/128, 4), blk, 0, stream>>>(
        ff_b, w2_l, nullptr, part, nullptr, nullptr, D_FF, D_FF/4, D_MODEL);
    reduce_ln<4><<<dim3(NTOK), dim3(128), 0, stream>>>(
        part, b2_l, ln2g + l*D_MODEL, ln2b + l*D_MODEL, h, h_b);
  }

  // 3) masked mean pool + lens output
  out_init<<<dim3((8192 + 16 + 255) / 256), blk, 0, stream>>>(out, lens);
  pool_kernel<<<dim3(SMAX/64, BATCH), blk, 0, stream>>>(h, lens, out);
}

// Round 8
// 813.520 us; speedup vs baseline: 1.0475x; 1.0345x over previous
//
#include <hip/hip_runtime.h>
#include <math.h>

// Problem constants
#define D_MODEL 512
#define NHEAD   8
#define DH      64
#define D_FF    2048
#define BATCH   16
#define SMAX    512
#define NTOK    (BATCH*SMAX)   // 8192
#define NLAYER  4

constexpr int MODE_QK   = 1;  // C cols 0..511 -> q rows (pre-scaled 1/8), 512..1023 -> k rows
constexpr int MODE_VT   = 2;  // C[m=feature][n=token] -> vt [bh][d][s], bias along m
constexpr int MODE_RELU = 3;  // Cb = bf16(relu(A*B^T + bias)), row-major
constexpr int MODE_PART = 4;  // Cb[z] = bf16(A*B^T) partial over K-chunk z

typedef __attribute__((ext_vector_type(8))) __bf16 bf16x8;
typedef __attribute__((ext_vector_type(4))) float  f32x4;

__device__ __forceinline__ unsigned short f2bf(float f) {
  union { float f; unsigned u; } v; v.f = f;
  unsigned r = v.u + 0x7FFFu + ((v.u >> 16) & 1u);   // RNE
  return (unsigned short)(r >> 16);
}
__device__ __forceinline__ float bf2f(unsigned short u) {
  union { unsigned u; float f; } v; v.u = ((unsigned)u) << 16; return v.f;
}

__device__ __forceinline__ void gl_lds16(const unsigned short* g, unsigned short* l) {
  __builtin_amdgcn_global_load_lds(
      (const __attribute__((address_space(1))) unsigned int*)g,
      (__attribute__((address_space(3)))       unsigned int*)l, 16, 0, 0);
}

// ---------------------------------------------------------------------------
// bf16 MFMA GEMM, 3-stage pipelined K-loop with raw vmcnt(4)+s_barrier.
// 256 threads = 4 waves (2x2), 128x128 tile, BK=32, 4x4 16x16x32 frags/wave.
// Length-aware: blocks whose token-tile is entirely padding return at once.
// Epilogue: wave-private LDS bounce -> dense 128B-line stores.
// ---------------------------------------------------------------------------
template<int MODE>
__global__ __launch_bounds__(256)
void gemm_mfma(const unsigned short* __restrict__ A,
               const unsigned short* __restrict__ Bw,
               const float* __restrict__ bias,
               unsigned short* __restrict__ Cb,
               unsigned short* __restrict__ qd, unsigned short* __restrict__ kd,
               const int* __restrict__ lens,
               int K, int CK, int N)
{
  const int m0 = blockIdx.y * 128, n0g = blockIdx.x * 128;
  // token-padding skip: row-major modes skip on m-tile; VT skips on token(n)-tile
  if (MODE == MODE_VT) {
    if ((n0g & 511) >= lens[n0g >> 9]) return;
  } else {
    if ((m0 & 511) >= lens[m0 >> 9]) return;
  }
  const int n0 = n0g;

  __shared__ __attribute__((aligned(16))) unsigned short As[3][128*32];
  __shared__ __attribute__((aligned(16))) unsigned short Bs[3][128*32];
  const int tid  = threadIdx.x;
  const int lane = tid & 63;
  const int w    = tid >> 6;
  const int wm   = (w & 1) * 64;
  const int wn   = (w >> 1) * 64;
  const int l15  = lane & 15, quad = lane >> 4;
  const int kz   = (MODE == MODE_PART) ? blockIdx.z : 0;

  f32x4 acc[4][4] = {};

  const int sr = tid >> 2;            // 0..63
  const int sk = (tid & 3) * 8;
  const unsigned short* Ag = A  + (long)(m0 + sr) * K + kz*CK + sk;
  const unsigned short* Bg = Bw + (long)(n0 + sr) * K + kz*CK + sk;
  const long rowskip = (long)64 * K;
  const int t8 = tid * 8;
  const int niter = CK >> 5;

  auto stage = [&](int t, int bix) {
    const unsigned short* a_ = Ag + t*32;
    const unsigned short* b_ = Bg + t*32;
    gl_lds16(a_,           &As[bix][t8]);
    gl_lds16(a_ + rowskip, &As[bix][2048 + t8]);
    gl_lds16(b_,           &Bs[bix][t8]);
    gl_lds16(b_ + rowskip, &Bs[bix][2048 + t8]);
  };

  stage(0, 0);
  stage(1, 1);

  for (int it = 0; it < niter; ++it) {
    if (it + 1 < niter)
      asm volatile("s_waitcnt vmcnt(4)\n\ts_barrier" ::: "memory");
    else
      asm volatile("s_waitcnt vmcnt(0)\n\ts_barrier" ::: "memory");
    if (it + 2 < niter) stage(it + 2, (it + 2) % 3);

    const int cur = it % 3;
    bf16x8 af[4], bfv[4];
#pragma unroll
    for (int i = 0; i < 4; i++)
      af[i] = *(const bf16x8*)&As[cur][(wm + i*16 + l15)*32 + quad*8];
#pragma unroll
    for (int j = 0; j < 4; j++)
      bfv[j] = *(const bf16x8*)&Bs[cur][(wn + j*16 + l15)*32 + quad*8];
#pragma unroll
    for (int i = 0; i < 4; i++)
#pragma unroll
      for (int j = 0; j < 4; j++)
        acc[i][j] = __builtin_amdgcn_mfma_f32_16x16x32_bf16(af[i], bfv[j], acc[i][j], 0, 0, 0);
  }

  // ---- epilogue: LDS bounce, dense 128B-line stores ----
  __syncthreads();
  unsigned short* epi = &As[0][0] + w * 1152;   // 16 rows x stride 72 per wave
  const int rr8 = lane >> 3, ch8 = lane & 7;
  const bool isq = (MODE == MODE_QK) && (((n0 + wn) >> 9) == 0);

#pragma unroll
  for (int i = 0; i < 4; i++) {
    float rbv[4];
    if (MODE == MODE_VT) {
#pragma unroll
      for (int r = 0; r < 4; r++) rbv[r] = bias[m0 + wm + i*16 + quad*4 + r];
    }
#pragma unroll
    for (int j = 0; j < 4; j++) {
      float cbv = 0.f;
      if (MODE == MODE_QK || MODE == MODE_RELU) cbv = bias[n0 + wn + j*16 + l15];
#pragma unroll
      for (int r = 0; r < 4; r++) {
        float v = acc[i][j][r];
        if (MODE == MODE_QK)   { v += cbv; if (isq) v *= 0.125f; }
        if (MODE == MODE_RELU) v = fmaxf(v + cbv, 0.f);
        if (MODE == MODE_VT)   v += rbv[r];
        epi[(quad*4 + r)*72 + j*16 + l15] = f2bf(v);
      }
    }
    asm volatile("s_waitcnt lgkmcnt(0)" ::: "memory");

#pragma unroll
    for (int rs = 0; rs < 2; rs++) {
      const int row  = rs*8 + rr8;
      const int mrow = m0 + wm + i*16 + row;
      bf16x8 val = *(const bf16x8*)&epi[row*72 + ch8*8];
      if (MODE == MODE_RELU) {
        *(bf16x8*)&Cb[(long)mrow*N + n0 + wn + ch8*8] = val;
      } else if (MODE == MODE_PART) {
        *(bf16x8*)&Cb[((long)kz*NTOK + mrow)*N + n0 + wn + ch8*8] = val;
      } else if (MODE == MODE_QK) {
        const int nb    = n0 + wn;
        const int which = nb >> 9;
        const int head  = (nb >> 6) & 7;
        unsigned short* dst = which ? kd : qd;
        const int bh = (mrow >> 9)*8 + head;
        *(bf16x8*)&dst[((long)(bh*512 + (mrow & 511)))*64 + ch8*8] = val;
      } else {  // MODE_VT
        const int head = mrow >> 6, d = mrow & 63;
        const int tok  = n0 + wn + ch8*8;
        const int b    = tok >> 9;
        *(bf16x8*)&Cb[((long)((b*8 + head)*64 + d))*512 + (tok & 511)] = val;
      }
    }
  }
}

// ---------------------------------------------------------------------------
// Fused split-K reduce + bias + residual + LayerNorm (padded rows skipped).
// ---------------------------------------------------------------------------
template<int KS>
__global__ __launch_bounds__(128)
void reduce_ln(const unsigned short* __restrict__ part,
               const float* __restrict__ bias,
               const float* __restrict__ g, const float* __restrict__ bb,
               float* __restrict__ h, unsigned short* __restrict__ hb,
               const int* __restrict__ lens)
{
  const int row = blockIdx.x, tid = threadIdx.x;
  if ((row & 511) >= lens[row >> 9]) return;
  float4 x  = ((const float4*)(h + (long)row*512))[tid];
  float4 bs = ((const float4*)bias)[tid];
  float v0 = x.x + bs.x, v1 = x.y + bs.y, v2 = x.z + bs.z, v3 = x.w + bs.w;
#pragma unroll
  for (int z = 0; z < KS; z++) {
    ushort4 p = ((const ushort4*)(part + ((long)z*NTOK + row)*512))[tid];
    v0 += bf2f(p.x); v1 += bf2f(p.y); v2 += bf2f(p.z); v3 += bf2f(p.w);
  }
  float s  = v0 + v1 + v2 + v3;
  float s2 = v0*v0 + v1*v1 + v2*v2 + v3*v3;
#pragma unroll
  for (int off = 1; off < 64; off <<= 1) {
    s  += __shfl_xor(s, off);
    s2 += __shfl_xor(s2, off);
  }
  __shared__ float rb[4];
  if ((tid & 63) == 0) { rb[(tid>>6)*2] = s; rb[(tid>>6)*2+1] = s2; }
  __syncthreads();
  s = rb[0] + rb[2]; s2 = rb[1] + rb[3];
  const float mean = s * (1.f/512.f);
  const float var  = fmaxf(s2 * (1.f/512.f) - mean*mean, 0.f);
  const float rstd = rsqrtf(var + 1e-5f);
  const int e = tid*4;
  float4 o;
  o.x = (v0-mean)*rstd*g[e+0] + bb[e+0];
  o.y = (v1-mean)*rstd*g[e+1] + bb[e+1];
  o.z = (v2-mean)*rstd*g[e+2] + bb[e+2];
  o.w = (v3-mean)*rstd*g[e+3] + bb[e+3];
  ((float4*)(h + (long)row*512))[tid] = o;
  ushort4 ob;
  ob.x = f2bf(o.x); ob.y = f2bf(o.y); ob.z = f2bf(o.z); ob.w = f2bf(o.w);
  ((ushort4*)(hb + (long)row*512))[tid] = ob;
}

// ---------------------------------------------------------------------------
// MFMA flash attention. Grid (bh, qt): all q-tiles of one (b,h) map to the
// SAME XCD (linear ids differ by multiples of 128 ≡ 0 mod 8) -> K/V L2 reuse.
// Q pre-scaled by 1/8 in QK epilogue; only the partial k-tile is masked.
// ---------------------------------------------------------------------------
__global__ __launch_bounds__(256)
void attn_mfma(const unsigned short* __restrict__ qg,
               const unsigned short* __restrict__ kb,
               const unsigned short* __restrict__ vtb,
               const int* __restrict__ lens,
               unsigned short* __restrict__ ctxb)
{
  const int bh = blockIdx.x, qt = blockIdx.y;
  const int b = bh >> 3, hh = bh & 7;
  const int len = lens[b];
  if (qt*64 >= len) return;

  __shared__ __attribute__((aligned(16))) unsigned short Ks[2][64*32*2];
  __shared__ __attribute__((aligned(16))) unsigned short Vts[2][64*32*2];
  __shared__ __attribute__((aligned(16))) unsigned short Ps[4*16*72];
  const int tid = threadIdx.x;
  const int w = tid >> 6, lane = tid & 63, l15 = lane & 15, quad = lane >> 4;
  const int t8 = tid * 8;

  const int srow = tid >> 2;
  const int s8   = (tid & 3) * 8;
  const unsigned short* Kbase = kb  + ((long)(bh*512 + srow))*64 + s8;
  const unsigned short* Vbase = vtb + ((long)(bh*64 + srow))*512 + s8;

  const unsigned short* qrow = qg + ((long)(bh*512 + qt*64 + w*16 + l15))*64;
  const bf16x8 qf0 = *(const bf16x8*)(qrow + quad*8);
  const bf16x8 qf1 = *(const bf16x8*)(qrow + 32 + quad*8);

  f32x4 O[4] = {};
  float mrow[4] = {-1e30f,-1e30f,-1e30f,-1e30f};
  float lrow[4] = {0.f,0.f,0.f,0.f};
  unsigned short* Pw = &Ps[w*16*72];
  const int ntiles = (len + 63) >> 6;

  {
    gl_lds16(Kbase,      &Ks[0][t8]);
    gl_lds16(Kbase + 32, &Ks[0][2048 + t8]);
    gl_lds16(Vbase,      &Vts[0][t8]);
    gl_lds16(Vbase + 32, &Vts[0][2048 + t8]);
  }

  for (int kt = 0; kt < ntiles; kt++) {
    const int cur = kt & 1;
    __syncthreads();
    if (kt + 1 < ntiles) {
      const unsigned short* Kg = Kbase + (long)(kt+1)*64*64;
      const unsigned short* Vg = Vbase + (long)(kt+1)*64;
      gl_lds16(Kg,      &Ks[cur^1][t8]);
      gl_lds16(Kg + 32, &Ks[cur^1][2048 + t8]);
      gl_lds16(Vg,      &Vts[cur^1][t8]);
      gl_lds16(Vg + 32, &Vts[cur^1][2048 + t8]);
    }

    f32x4 sc[4];
#pragma unroll
    for (int ks = 0; ks < 4; ks++) {
      bf16x8 kf0 = *(const bf16x8*)&Ks[cur][       (ks*16 + l15)*32 + quad*8];
      bf16x8 kf1 = *(const bf16x8*)&Ks[cur][2048 + (ks*16 + l15)*32 + quad*8];
      f32x4 z = {};
      z = __builtin_amdgcn_mfma_f32_16x16x32_bf16(qf0, kf0, z, 0, 0, 0);
      sc[ks] = __builtin_amdgcn_mfma_f32_16x16x32_bf16(qf1, kf1, z, 0, 0, 0);
    }

    if (kt*64 + 64 > len) {   // only the single partial tile needs masking
#pragma unroll
      for (int ks = 0; ks < 4; ks++) {
        const bool valid = (kt*64 + ks*16 + l15) < len;
#pragma unroll
        for (int r = 0; r < 4; r++)
          sc[ks][r] = valid ? sc[ks][r] : -1e30f;
      }
    }

    float pv[4][4];
#pragma unroll
    for (int r = 0; r < 4; r++) {
      float mx = fmaxf(fmaxf(sc[0][r], sc[1][r]), fmaxf(sc[2][r], sc[3][r]));
      mx = fmaxf(mx, __shfl_xor(mx, 1));
      mx = fmaxf(mx, __shfl_xor(mx, 2));
      mx = fmaxf(mx, __shfl_xor(mx, 4));
      mx = fmaxf(mx, __shfl_xor(mx, 8));
      const float newm  = fmaxf(mrow[r], mx);
      const float alpha = __expf(mrow[r] - newm);
      float ps = 0.f;
#pragma unroll
      for (int ks = 0; ks < 4; ks++) { pv[ks][r] = __expf(sc[ks][r] - newm); ps += pv[ks][r]; }
      ps += __shfl_xor(ps, 1); ps += __shfl_xor(ps, 2);
      ps += __shfl_xor(ps, 4); ps += __shfl_xor(ps, 8);
      lrow[r] = lrow[r]*alpha + ps;
      mrow[r] = newm;
#pragma unroll
      for (int d = 0; d < 4; d++) O[d][r] *= alpha;
    }

#pragma unroll
    for (int ks = 0; ks < 4; ks++)
#pragma unroll
      for (int r = 0; r < 4; r++)
        Pw[(quad*4 + r)*72 + ks*16 + l15] = f2bf(pv[ks][r]);
    asm volatile("s_waitcnt lgkmcnt(0)" ::: "memory");

    const bf16x8 pa0 = *(const bf16x8*)&Pw[l15*72 + quad*8];
    const bf16x8 pa1 = *(const bf16x8*)&Pw[l15*72 + 32 + quad*8];
#pragma unroll
    for (int d = 0; d < 4; d++) {
      bf16x8 vf0 = *(const bf16x8*)&Vts[cur][       (d*16 + l15)*32 + quad*8];
      bf16x8 vf1 = *(const bf16x8*)&Vts[cur][2048 + (d*16 + l15)*32 + quad*8];
      O[d] = __builtin_amdgcn_mfma_f32_16x16x32_bf16(pa0, vf0, O[d], 0, 0, 0);
      O[d] = __builtin_amdgcn_mfma_f32_16x16x32_bf16(pa1, vf1, O[d], 0, 0, 0);
    }
  }

  // ctx write via wave-private LDS bounce -> dense 128B stores
#pragma unroll
  for (int r = 0; r < 4; r++) {
    const float inv = 1.f / lrow[r];
#pragma unroll
    for (int d = 0; d < 4; d++)
      Pw[(quad*4 + r)*72 + d*16 + l15] = f2bf(O[d][r] * inv);
  }
  asm volatile("s_waitcnt lgkmcnt(0)" ::: "memory");
  {
    const int rr8 = lane >> 3, ch8 = lane & 7;
#pragma unroll
    for (int rs = 0; rs < 2; rs++) {
      const int row = rs*8 + rr8;
      const long gaddr = (long)(b*512 + qt*64 + w*16 + row)*512 + hh*64 + ch8*8;
      *(bf16x8*)&ctxb[gaddr] = *(const bf16x8*)&Pw[row*72 + ch8*8];
    }
  }
}

// ---------------------------------------------------------------------------
// fp32 embedding GEMM (K=80): h = x*We^T + be + posenc; writes fp32 + bf16.
// ---------------------------------------------------------------------------
__global__ __launch_bounds__(256)
void gemm_embed(const float* __restrict__ A, const float* __restrict__ Bm,
                const float* __restrict__ bias, float* __restrict__ C,
                unsigned short* __restrict__ Cb, int K, int N)
{
  __shared__ float As[8][132];
  __shared__ float Bs[8][68];
  const int tid = threadIdx.x;
  const int m0 = blockIdx.y * 128;
  const int n0 = blockIdx.x * 64;
  const int tx = tid & 15, ty = tid >> 4;
  const int a_k = tid & 7, a_m = tid >> 3;

  float acc[8][4] = {};
  const float* Ag = A  + (long)(m0 + a_m) * K + a_k;
  const float* Bg = Bm + (long)(n0 + a_m) * K + a_k;

  for (int k0 = 0; k0 < K; k0 += 8) {
#pragma unroll
    for (int i = 0; i < 4; i++)
      As[a_k][a_m + 32*i] = Ag[k0 + (long)32*i*K];
#pragma unroll
    for (int i = 0; i < 2; i++)
      Bs[a_k][a_m + 32*i] = Bg[k0 + (long)32*i*K];
    __syncthreads();
#pragma unroll
    for (int kk = 0; kk < 8; kk++) {
      float a[8], bv[4];
#pragma unroll
      for (int r = 0; r < 8; r++) a[r] = As[kk][ty*8 + r];
#pragma unroll
      for (int c = 0; c < 4; c++) bv[c] = Bs[kk][tx*4 + c];
#pragma unroll
      for (int r = 0; r < 8; r++)
#pragma unroll
        for (int c = 0; c < 4; c++)
          acc[r][c] += a[r] * bv[c];
    }
    __syncthreads();
  }

  const int n_base = n0 + tx*4;
#pragma unroll
  for (int r = 0; r < 8; r++) {
    int m = m0 + ty*8 + r;
    int s = m & 511;
    float4 v4; float* vp = &v4.x;
#pragma unroll
    for (int c = 0; c < 4; c++) {
      int e = n_base + c;
      float dv  = __expf((float)(e & ~1) * (-9.210340371976184f / 512.0f));
      float ang = (float)s * dv;
      vp[c] = acc[r][c] + bias[e] + ((e & 1) ? cosf(ang) : sinf(ang));
    }
    *(float4*)(C + (long)m*N + n_base) = v4;
    ushort4 ob;
    ob.x = f2bf(v4.x); ob.y = f2bf(v4.y); ob.z = f2bf(v4.z); ob.w = f2bf(v4.w);
    *(ushort4*)(Cb + (long)m*N + n_base) = ob;
  }
}

// fp32 -> bf16 cast of all 4 weight tensors in one dispatch
#define N4_QKV (NLAYER*3*D_MODEL*D_MODEL/4)
#define N4_WO  (NLAYER*D_MODEL*D_MODEL/4)
#define N4_W1  (NLAYER*D_FF*D_MODEL/4)
#define N4_W2  (NLAYER*D_MODEL*D_FF/4)
__global__ __launch_bounds__(256)
void cvt_all(const float* __restrict__ wq, const float* __restrict__ wo,
             const float* __restrict__ w1, const float* __restrict__ w2,
             unsigned short* __restrict__ oq, unsigned short* __restrict__ oo,
             unsigned short* __restrict__ o1, unsigned short* __restrict__ o2)
{
  int i = blockIdx.x*256 + threadIdx.x;
  const float* src; unsigned short* dst; int off;
  if (i < N4_QKV)                          { src = wq; dst = oq; off = i; }
  else if (i < N4_QKV + N4_WO)             { src = wo; dst = oo; off = i - N4_QKV; }
  else if (i < N4_QKV + N4_WO + N4_W1)     { src = w1; dst = o1; off = i - N4_QKV - N4_WO; }
  else if (i < N4_QKV + N4_WO + N4_W1 + N4_W2) { src = w2; dst = o2; off = i - N4_QKV - N4_WO - N4_W1; }
  else return;
  float4 v = ((const float4*)src)[off];
  ushort4 o;
  o.x = f2bf(v.x); o.y = f2bf(v.y); o.z = f2bf(v.z); o.w = f2bf(v.w);
  ((ushort4*)dst)[off] = o;
}

__global__ __launch_bounds__(256)
void out_init(float* __restrict__ out, const int* __restrict__ lens)
{
  int i = blockIdx.x*256 + threadIdx.x;
  if (i < 8192) out[i] = 0.f;
  else if (i < 8192 + 16) out[i] = (float)lens[i - 8192];
}

__global__ __launch_bounds__(256)
void pool_kernel(const float* __restrict__ h, const int* __restrict__ lens,
                 float* __restrict__ out)
{
  const int b = blockIdx.y;
  const int s0 = blockIdx.x * 64;
  const int len = lens[b];
  if (s0 >= len) return;
  const int send = min(s0 + 64, len);
  const int tid = threadIdx.x;
  float acc0 = 0.f, acc1 = 0.f;
  for (int s = s0; s < send; s++) {
    const float* row = h + (long)(b*512 + s)*512;
    acc0 += row[tid];
    acc1 += row[tid + 256];
  }
  const float inv = 1.0f / (float)len;
  atomicAdd(out + b*512 + tid,       acc0 * inv);
  atomicAdd(out + b*512 + tid + 256, acc1 * inv);
}

// ---------------------------------------------------------------------------
extern "C" void kernel_launch(void* const* d_in, const int* in_sizes, int n_in,
                              void* d_out, int out_size, void* d_ws, size_t ws_size,
                              hipStream_t stream)
{
  const float* x    = (const float*)d_in[0];
  const int*   lens = (const int*)  d_in[1];
  const float* We   = (const float*)d_in[2];
  const float* be   = (const float*)d_in[3];
  const float* Wqkv = (const float*)d_in[4];
  const float* bqkv = (const float*)d_in[5];
  const float* Wo   = (const float*)d_in[6];
  const float* bo   = (const float*)d_in[7];
  const float* ln1g = (const float*)d_in[8];
  const float* ln1b = (const float*)d_in[9];
  const float* W1   = (const float*)d_in[10];
  const float* b1   = (const float*)d_in[11];
  const float* W2   = (const float*)d_in[12];
  const float* b2   = (const float*)d_in[13];
  const float* ln2g = (const float*)d_in[14];
  const float* ln2b = (const float*)d_in[15];
  float* out = (float*)d_out;

  // Workspace layout
  const long TOK_D = (long)NTOK * D_MODEL;              // 4,194,304
  float* ws  = (float*)d_ws;
  float* h   = ws;                                      // fp32 [8192,512]
  unsigned short* us    = (unsigned short*)(ws + 1*TOK_D);
  unsigned short* h_b   = us;                           // bf16 [8192,512]
  unsigned short* ctx_b = us + 1*TOK_D;
  unsigned short* q_b   = us + 2*TOK_D;                 // [bh][s][64] (pre-scaled 1/8)
  unsigned short* k_b   = us + 3*TOK_D;                 // [bh][s][64]
  unsigned short* vt_b  = us + 4*TOK_D;                 // [bh][d][s]
  unsigned short* ff_b  = us + 5*TOK_D;                 // bf16 [8192,2048]
  unsigned short* wq_b  = us + 9*TOK_D;
  unsigned short* wo_b  = wq_b + (long)NLAYER*3*D_MODEL*D_MODEL;
  unsigned short* w1_b  = wo_b + (long)NLAYER*D_MODEL*D_MODEL;
  unsigned short* w2_b  = w1_b + (long)NLAYER*D_FF*D_MODEL;
  unsigned short* part  = w2_b + (long)NLAYER*D_MODEL*D_FF;  // [<=4][8192][512]

  const dim3 blk(256);

  // 0) all weight casts in one dispatch
  {
    const int n4tot = N4_QKV + N4_WO + N4_W1 + N4_W2;
    cvt_all<<<dim3((n4tot+255)/256), blk, 0, stream>>>(
        Wqkv, Wo, W1, W2, wq_b, wo_b, w1_b, w2_b);
  }

  // 1) embedding + posenc (fp32), writes h + h_b
  gemm_embed<<<dim3(D_MODEL/64, NTOK/128), blk, 0, stream>>>(
      x, We, be, h, h_b, 80, D_MODEL);

  for (int l = 0; l < NLAYER; l++) {
    const unsigned short* wq_l = wq_b + (long)l * 3*D_MODEL * D_MODEL;
    const unsigned short* wo_l = wo_b + (long)l * D_MODEL * D_MODEL;
    const unsigned short* w1_l = w1_b + (long)l * D_FF * D_MODEL;
    const unsigned short* w2_l = w2_b + (long)l * D_MODEL * D_FF;
    const float* bqkv_l = bqkv + (long)l * 3*D_MODEL;
    const float* bo_l   = bo   + (long)l * D_MODEL;
    const float* b1_l   = b1   + (long)l * D_FF;
    const float* b2_l   = b2   + (long)l * D_MODEL;

    // q,k = h*Wqk^T + b  -> row-major [bh][s][64], q pre-scaled by 1/8
    gemm_mfma<MODE_QK><<<dim3(2*D_MODEL/128, NTOK/128), blk, 0, stream>>>(
        h_b, wq_l, bqkv_l, nullptr, q_b, k_b, lens, D_MODEL, D_MODEL, 2*D_MODEL);

    // v^T = Wv*h^T + bv -> [bh][d][s]
    gemm_mfma<MODE_VT><<<dim3(NTOK/128, D_MODEL/128), blk, 0, stream>>>(
        wq_l + (long)2*D_MODEL*D_MODEL, h_b, bqkv_l + 2*D_MODEL, vt_b,
        nullptr, nullptr, lens, D_MODEL, D_MODEL, NTOK);

    // attention -> ctx_b ; grid (bh, qt) for XCD-local K/V reuse
    attn_mfma<<<dim3(NHEAD*BATCH, SMAX/64), blk, 0, stream>>>(
        q_b, k_b, vt_b, lens, ctx_b);

    // Wo partials: split-K x2 (CK=256), then fused reduce+resid+LN1
    gemm_mfma<MODE_PART><<<dim3(D_MODEL/128, NTOK/128, 2), blk, 0, stream>>>(
        ctx_b, wo_l, nullptr, part, nullptr, nullptr, lens, D_MODEL, D_MODEL/2, D_MODEL);
    reduce_ln<2><<<dim3(NTOK), dim3(128), 0, stream>>>(
        part, bo_l, ln1g + l*D_MODEL, ln1b + l*D_MODEL, h, h_b, lens);

    // ff_b = bf16(relu(h*W1^T + b1))
    gemm_mfma<MODE_RELU><<<dim3(D_FF/128, NTOK/128), blk, 0, stream>>>(
        h_b, w1_l, b1_l, ff_b, nullptr, nullptr, lens, D_MODEL, D_MODEL, D_FF);

    // FF2 partials: split-K x4 (CK=512), then fused reduce+resid+LN2
    gemm_mfma<MODE_PART><<<dim3(D_MODEL/128, NTOK/128, 4), blk, 0, stream>>>(
        ff_b, w2_l, nullptr, part, nullptr, nullptr, lens, D_FF, D_FF/4, D_MODEL);
    reduce_ln<4><<<dim3(NTOK), dim3(128), 0, stream>>>(
        part, b2_l, ln2g + l*D_MODEL, ln2b + l*D_MODEL, h, h_b, lens);
  }

  // 3) masked mean pool + lens output
  out_init<<<dim3((8192 + 16 + 255) / 256), blk, 0, stream>>>(out, lens);
  pool_kernel<<<dim3(SMAX/64, BATCH), blk, 0, stream>>>(h, lens, out);
}

// Round 9
// 755.813 us; speedup vs baseline: 1.1275x; 1.0764x over previous
//
#include <hip/hip_runtime.h>
#include <math.h>

// Problem constants
#define D_MODEL 512
#define NHEAD   8
#define DH      64
#define D_FF    2048
#define BATCH   16
#define SMAX    512
#define NTOK    (BATCH*SMAX)   // 8192
#define NLAYER  4

constexpr int MODE_QK   = 1;  // C cols 0..511 -> q rows (pre-scaled 1/8), 512..1023 -> k rows
constexpr int MODE_VT   = 2;  // C[m=feature][n=token] -> vt [bh][d][s], bias along m
constexpr int MODE_RELU = 3;  // Cb = bf16(relu(A*B^T + bias)), row-major
constexpr int MODE_PART = 4;  // Cb[z] = bf16(A*B^T) partial over K-chunk z

typedef __attribute__((ext_vector_type(8))) __bf16 bf16x8;
typedef __attribute__((ext_vector_type(4))) float  f32x4;

__device__ __forceinline__ unsigned short f2bf(float f) {
  union { float f; unsigned u; } v; v.f = f;
  unsigned r = v.u + 0x7FFFu + ((v.u >> 16) & 1u);   // RNE
  return (unsigned short)(r >> 16);
}
__device__ __forceinline__ float bf2f(unsigned short u) {
  union { unsigned u; float f; } v; v.u = ((unsigned)u) << 16; return v.f;
}

__device__ __forceinline__ void gl_lds16(const unsigned short* g, unsigned short* l) {
  __builtin_amdgcn_global_load_lds(
      (const __attribute__((address_space(1))) unsigned int*)g,
      (__attribute__((address_space(3)))       unsigned int*)l, 16, 0, 0);
}

// ---------------------------------------------------------------------------
// bf16 MFMA GEMM, 3-stage pipelined K-loop with raw vmcnt(4)+s_barrier.
// XCD-aware block remap: blocks sharing the LARGE operand tile are congruent
// mod 8 (same XCD) -> that tile is fetched once per XCD instead of 8x.
// ---------------------------------------------------------------------------
template<int MODE>
__global__ __launch_bounds__(256)
void gemm_mfma(const unsigned short* __restrict__ A,
               const unsigned short* __restrict__ Bw,
               const float* __restrict__ bias,
               unsigned short* __restrict__ Cb,
               unsigned short* __restrict__ qd, unsigned short* __restrict__ kd,
               const int* __restrict__ lens,
               int K, int CK, int N)
{
  // XCD-aware swizzle (HW dispatch order = x-fastest linearization, XCD = lin%8)
  const int lin = blockIdx.x + gridDim.x*(blockIdx.y + gridDim.y*blockIdx.z);
  int m0, n0, kz = 0;
  if (MODE == MODE_VT) {
    // big operand = B (token rows): group n-tiles mod 8
    n0 = (lin % gridDim.x) * 128;
    m0 = (lin / gridDim.x) * 128;
  } else {
    // big operand = A (token rows): group m-tiles mod 8
    m0 = (lin % gridDim.y) * 128;
    const int rest = lin / gridDim.y;
    n0 = (rest % gridDim.x) * 128;
    kz = rest / gridDim.x;            // PART only (gz=1 otherwise)
  }
  // token-padding skip
  if (MODE == MODE_VT) {
    if ((n0 & 511) >= lens[n0 >> 9]) return;
  } else {
    if ((m0 & 511) >= lens[m0 >> 9]) return;
  }

  __shared__ __attribute__((aligned(16))) unsigned short As[3][128*32];
  __shared__ __attribute__((aligned(16))) unsigned short Bs[3][128*32];
  const int tid  = threadIdx.x;
  const int lane = tid & 63;
  const int w    = tid >> 6;
  const int wm   = (w & 1) * 64;
  const int wn   = (w >> 1) * 64;
  const int l15  = lane & 15, quad = lane >> 4;

  f32x4 acc[4][4] = {};

  const int sr = tid >> 2;            // 0..63
  const int sk = (tid & 3) * 8;
  const unsigned short* Ag = A  + (long)(m0 + sr) * K + kz*CK + sk;
  const unsigned short* Bg = Bw + (long)(n0 + sr) * K + kz*CK + sk;
  const long rowskip = (long)64 * K;
  const int t8 = tid * 8;
  const int niter = CK >> 5;

  auto stage = [&](int t, int bix) {
    const unsigned short* a_ = Ag + t*32;
    const unsigned short* b_ = Bg + t*32;
    gl_lds16(a_,           &As[bix][t8]);
    gl_lds16(a_ + rowskip, &As[bix][2048 + t8]);
    gl_lds16(b_,           &Bs[bix][t8]);
    gl_lds16(b_ + rowskip, &Bs[bix][2048 + t8]);
  };

  stage(0, 0);
  stage(1, 1);

  for (int it = 0; it < niter; ++it) {
    if (it + 1 < niter)
      asm volatile("s_waitcnt vmcnt(4)\n\ts_barrier" ::: "memory");
    else
      asm volatile("s_waitcnt vmcnt(0)\n\ts_barrier" ::: "memory");
    if (it + 2 < niter) stage(it + 2, (it + 2) % 3);

    const int cur = it % 3;
    bf16x8 af[4], bfv[4];
#pragma unroll
    for (int i = 0; i < 4; i++)
      af[i] = *(const bf16x8*)&As[cur][(wm + i*16 + l15)*32 + quad*8];
#pragma unroll
    for (int j = 0; j < 4; j++)
      bfv[j] = *(const bf16x8*)&Bs[cur][(wn + j*16 + l15)*32 + quad*8];
#pragma unroll
    for (int i = 0; i < 4; i++)
#pragma unroll
      for (int j = 0; j < 4; j++)
        acc[i][j] = __builtin_amdgcn_mfma_f32_16x16x32_bf16(af[i], bfv[j], acc[i][j], 0, 0, 0);
  }

  // ---- epilogue: LDS bounce, dense 128B-line stores ----
  __syncthreads();
  unsigned short* epi = &As[0][0] + w * 1152;   // 16 rows x stride 72 per wave
  const int rr8 = lane >> 3, ch8 = lane & 7;
  const bool isq = (MODE == MODE_QK) && (((n0 + wn) >> 9) == 0);

#pragma unroll
  for (int i = 0; i < 4; i++) {
    float rbv[4];
    if (MODE == MODE_VT) {
#pragma unroll
      for (int r = 0; r < 4; r++) rbv[r] = bias[m0 + wm + i*16 + quad*4 + r];
    }
#pragma unroll
    for (int j = 0; j < 4; j++) {
      float cbv = 0.f;
      if (MODE == MODE_QK || MODE == MODE_RELU) cbv = bias[n0 + wn + j*16 + l15];
#pragma unroll
      for (int r = 0; r < 4; r++) {
        float v = acc[i][j][r];
        if (MODE == MODE_QK)   { v += cbv; if (isq) v *= 0.125f; }
        if (MODE == MODE_RELU) v = fmaxf(v + cbv, 0.f);
        if (MODE == MODE_VT)   v += rbv[r];
        epi[(quad*4 + r)*72 + j*16 + l15] = f2bf(v);
      }
    }
    asm volatile("s_waitcnt lgkmcnt(0)" ::: "memory");

#pragma unroll
    for (int rs = 0; rs < 2; rs++) {
      const int row  = rs*8 + rr8;
      const int mrow = m0 + wm + i*16 + row;
      bf16x8 val = *(const bf16x8*)&epi[row*72 + ch8*8];
      if (MODE == MODE_RELU) {
        *(bf16x8*)&Cb[(long)mrow*N + n0 + wn + ch8*8] = val;
      } else if (MODE == MODE_PART) {
        *(bf16x8*)&Cb[((long)kz*NTOK + mrow)*N + n0 + wn + ch8*8] = val;
      } else if (MODE == MODE_QK) {
        const int nb    = n0 + wn;
        const int which = nb >> 9;
        const int head  = (nb >> 6) & 7;
        unsigned short* dst = which ? kd : qd;
        const int bh = (mrow >> 9)*8 + head;
        *(bf16x8*)&dst[((long)(bh*512 + (mrow & 511)))*64 + ch8*8] = val;
      } else {  // MODE_VT
        const int head = mrow >> 6, d = mrow & 63;
        const int tok  = n0 + wn + ch8*8;
        const int b    = tok >> 9;
        *(bf16x8*)&Cb[((long)((b*8 + head)*64 + d))*512 + (tok & 511)] = val;
      }
    }
  }
}

// ---------------------------------------------------------------------------
// Fused split-K reduce + bias + bf16 residual + LayerNorm (padded rows skip).
// Residual AND output live in hb (bf16) — no fp32 stream.
// ---------------------------------------------------------------------------
template<int KS>
__global__ __launch_bounds__(128)
void reduce_ln(const unsigned short* __restrict__ part,
               const float* __restrict__ bias,
               const float* __restrict__ g, const float* __restrict__ bb,
               unsigned short* __restrict__ hb,
               const int* __restrict__ lens)
{
  const int row = blockIdx.x, tid = threadIdx.x;
  if ((row & 511) >= lens[row >> 9]) return;
  ushort4 hx = ((const ushort4*)(hb + (long)row*512))[tid];
  float4 bs  = ((const float4*)bias)[tid];
  float v0 = bf2f(hx.x) + bs.x, v1 = bf2f(hx.y) + bs.y;
  float v2 = bf2f(hx.z) + bs.z, v3 = bf2f(hx.w) + bs.w;
#pragma unroll
  for (int z = 0; z < KS; z++) {
    ushort4 p = ((const ushort4*)(part + ((long)z*NTOK + row)*512))[tid];
    v0 += bf2f(p.x); v1 += bf2f(p.y); v2 += bf2f(p.z); v3 += bf2f(p.w);
  }
  float s  = v0 + v1 + v2 + v3;
  float s2 = v0*v0 + v1*v1 + v2*v2 + v3*v3;
#pragma unroll
  for (int off = 1; off < 64; off <<= 1) {
    s  += __shfl_xor(s, off);
    s2 += __shfl_xor(s2, off);
  }
  __shared__ float rb[4];
  if ((tid & 63) == 0) { rb[(tid>>6)*2] = s; rb[(tid>>6)*2+1] = s2; }
  __syncthreads();
  s = rb[0] + rb[2]; s2 = rb[1] + rb[3];
  const float mean = s * (1.f/512.f);
  const float var  = fmaxf(s2 * (1.f/512.f) - mean*mean, 0.f);
  const float rstd = rsqrtf(var + 1e-5f);
  const int e = tid*4;
  ushort4 ob;
  ob.x = f2bf((v0-mean)*rstd*g[e+0] + bb[e+0]);
  ob.y = f2bf((v1-mean)*rstd*g[e+1] + bb[e+1]);
  ob.z = f2bf((v2-mean)*rstd*g[e+2] + bb[e+2]);
  ob.w = f2bf((v3-mean)*rstd*g[e+3] + bb[e+3]);
  ((ushort4*)(hb + (long)row*512))[tid] = ob;
}

// ---------------------------------------------------------------------------
// MFMA flash attention (round-7 structure, grid (bh, qt) for XCD K/V reuse).
// ---------------------------------------------------------------------------
__global__ __launch_bounds__(256)
void attn_mfma(const unsigned short* __restrict__ qg,
               const unsigned short* __restrict__ kb,
               const unsigned short* __restrict__ vtb,
               const int* __restrict__ lens,
               unsigned short* __restrict__ ctxb)
{
  const int bh = blockIdx.x, qt = blockIdx.y;
  const int b = bh >> 3, hh = bh & 7;
  const int len = lens[b];
  if (qt*64 >= len) return;

  __shared__ __attribute__((aligned(16))) unsigned short Ks[2][64*32*2];
  __shared__ __attribute__((aligned(16))) unsigned short Vts[2][64*32*2];
  __shared__ __attribute__((aligned(16))) unsigned short Ps[4*16*72];
  const int tid = threadIdx.x;
  const int w = tid >> 6, lane = tid & 63, l15 = lane & 15, quad = lane >> 4;
  const int t8 = tid * 8;

  const int srow = tid >> 2;
  const int s8   = (tid & 3) * 8;
  const unsigned short* Kbase = kb  + ((long)(bh*512 + srow))*64 + s8;
  const unsigned short* Vbase = vtb + ((long)(bh*64 + srow))*512 + s8;

  const unsigned short* qrow = qg + ((long)(bh*512 + qt*64 + w*16 + l15))*64;
  const bf16x8 qf0 = *(const bf16x8*)(qrow + quad*8);
  const bf16x8 qf1 = *(const bf16x8*)(qrow + 32 + quad*8);

  f32x4 O[4] = {};
  float mrow[4] = {-1e30f,-1e30f,-1e30f,-1e30f};
  float lrow[4] = {0.f,0.f,0.f,0.f};
  unsigned short* Pw = &Ps[w*16*72];
  const int ntiles = (len + 63) >> 6;

  {
    gl_lds16(Kbase,      &Ks[0][t8]);
    gl_lds16(Kbase + 32, &Ks[0][2048 + t8]);
    gl_lds16(Vbase,      &Vts[0][t8]);
    gl_lds16(Vbase + 32, &Vts[0][2048 + t8]);
  }

  for (int kt = 0; kt < ntiles; kt++) {
    const int cur = kt & 1;
    __syncthreads();
    if (kt + 1 < ntiles) {
      const unsigned short* Kg = Kbase + (long)(kt+1)*64*64;
      const unsigned short* Vg = Vbase + (long)(kt+1)*64;
      gl_lds16(Kg,      &Ks[cur^1][t8]);
      gl_lds16(Kg + 32, &Ks[cur^1][2048 + t8]);
      gl_lds16(Vg,      &Vts[cur^1][t8]);
      gl_lds16(Vg + 32, &Vts[cur^1][2048 + t8]);
    }

    f32x4 sc[4];
#pragma unroll
    for (int ks = 0; ks < 4; ks++) {
      bf16x8 kf0 = *(const bf16x8*)&Ks[cur][       (ks*16 + l15)*32 + quad*8];
      bf16x8 kf1 = *(const bf16x8*)&Ks[cur][2048 + (ks*16 + l15)*32 + quad*8];
      f32x4 z = {};
      z = __builtin_amdgcn_mfma_f32_16x16x32_bf16(qf0, kf0, z, 0, 0, 0);
      sc[ks] = __builtin_amdgcn_mfma_f32_16x16x32_bf16(qf1, kf1, z, 0, 0, 0);
    }

    if (kt*64 + 64 > len) {
#pragma unroll
      for (int ks = 0; ks < 4; ks++) {
        const bool valid = (kt*64 + ks*16 + l15) < len;
#pragma unroll
        for (int r = 0; r < 4; r++)
          sc[ks][r] = valid ? sc[ks][r] : -1e30f;
      }
    }

    float pv[4][4];
#pragma unroll
    for (int r = 0; r < 4; r++) {
      float mx = fmaxf(fmaxf(sc[0][r], sc[1][r]), fmaxf(sc[2][r], sc[3][r]));
      mx = fmaxf(mx, __shfl_xor(mx, 1));
      mx = fmaxf(mx, __shfl_xor(mx, 2));
      mx = fmaxf(mx, __shfl_xor(mx, 4));
      mx = fmaxf(mx, __shfl_xor(mx, 8));
      const float newm  = fmaxf(mrow[r], mx);
      const float alpha = __expf(mrow[r] - newm);
      float ps = 0.f;
#pragma unroll
      for (int ks = 0; ks < 4; ks++) { pv[ks][r] = __expf(sc[ks][r] - newm); ps += pv[ks][r]; }
      ps += __shfl_xor(ps, 1); ps += __shfl_xor(ps, 2);
      ps += __shfl_xor(ps, 4); ps += __shfl_xor(ps, 8);
      lrow[r] = lrow[r]*alpha + ps;
      mrow[r] = newm;
#pragma unroll
      for (int d = 0; d < 4; d++) O[d][r] *= alpha;
    }

#pragma unroll
    for (int ks = 0; ks < 4; ks++)
#pragma unroll
      for (int r = 0; r < 4; r++)
        Pw[(quad*4 + r)*72 + ks*16 + l15] = f2bf(pv[ks][r]);
    asm volatile("s_waitcnt lgkmcnt(0)" ::: "memory");

    const bf16x8 pa0 = *(const bf16x8*)&Pw[l15*72 + quad*8];
    const bf16x8 pa1 = *(const bf16x8*)&Pw[l15*72 + 32 + quad*8];
#pragma unroll
    for (int d = 0; d < 4; d++) {
      bf16x8 vf0 = *(const bf16x8*)&Vts[cur][       (d*16 + l15)*32 + quad*8];
      bf16x8 vf1 = *(const bf16x8*)&Vts[cur][2048 + (d*16 + l15)*32 + quad*8];
      O[d] = __builtin_amdgcn_mfma_f32_16x16x32_bf16(pa0, vf0, O[d], 0, 0, 0);
      O[d] = __builtin_amdgcn_mfma_f32_16x16x32_bf16(pa1, vf1, O[d], 0, 0, 0);
    }
  }

#pragma unroll
  for (int r = 0; r < 4; r++) {
    const float inv = 1.f / lrow[r];
#pragma unroll
    for (int d = 0; d < 4; d++)
      Pw[(quad*4 + r)*72 + d*16 + l15] = f2bf(O[d][r] * inv);
  }
  asm volatile("s_waitcnt lgkmcnt(0)" ::: "memory");
  {
    const int rr8 = lane >> 3, ch8 = lane & 7;
#pragma unroll
    for (int rs = 0; rs < 2; rs++) {
      const int row = rs*8 + rr8;
      const long gaddr = (long)(b*512 + qt*64 + w*16 + row)*512 + hh*64 + ch8*8;
      *(bf16x8*)&ctxb[gaddr] = *(const bf16x8*)&Pw[row*72 + ch8*8];
    }
  }
}

// ---------------------------------------------------------------------------
// Positional-encoding table: pe[s][e], computed once per launch (fp32).
// ---------------------------------------------------------------------------
__global__ __launch_bounds__(256)
void pe_kernel(float* __restrict__ pe)
{
  const int i = blockIdx.x*256 + threadIdx.x;   // i < 512*512
  const int s = i >> 9, e = i & 511;
  const float dv  = __expf((float)(e & ~1) * (-9.210340371976184f / 512.0f));
  const float ang = (float)s * dv;
  pe[i] = (e & 1) ? cosf(ang) : sinf(ang);
}

// ---------------------------------------------------------------------------
// fp32 embedding GEMM (K=80): h_b = bf16(x*We^T + be + pe[s]).
// ---------------------------------------------------------------------------
__global__ __launch_bounds__(256)
void gemm_embed(const float* __restrict__ A, const float* __restrict__ Bm,
                const float* __restrict__ bias, const float* __restrict__ pe,
                unsigned short* __restrict__ Cb, int K, int N)
{
  __shared__ float As[8][132];
  __shared__ float Bs[8][68];
  const int tid = threadIdx.x;
  const int m0 = blockIdx.y * 128;
  const int n0 = blockIdx.x * 64;
  const int tx = tid & 15, ty = tid >> 4;
  const int a_k = tid & 7, a_m = tid >> 3;

  float acc[8][4] = {};
  const float* Ag = A  + (long)(m0 + a_m) * K + a_k;
  const float* Bg = Bm + (long)(n0 + a_m) * K + a_k;

  for (int k0 = 0; k0 < K; k0 += 8) {
#pragma unroll
    for (int i = 0; i < 4; i++)
      As[a_k][a_m + 32*i] = Ag[k0 + (long)32*i*K];
#pragma unroll
    for (int i = 0; i < 2; i++)
      Bs[a_k][a_m + 32*i] = Bg[k0 + (long)32*i*K];
    __syncthreads();
#pragma unroll
    for (int kk = 0; kk < 8; kk++) {
      float a[8], bv[4];
#pragma unroll
      for (int r = 0; r < 8; r++) a[r] = As[kk][ty*8 + r];
#pragma unroll
      for (int c = 0; c < 4; c++) bv[c] = Bs[kk][tx*4 + c];
#pragma unroll
      for (int r = 0; r < 8; r++)
#pragma unroll
        for (int c = 0; c < 4; c++)
          acc[r][c] += a[r] * bv[c];
    }
    __syncthreads();
  }

  const int n_base = n0 + tx*4;
#pragma unroll
  for (int r = 0; r < 8; r++) {
    int m = m0 + ty*8 + r;
    int s = m & 511;
    float4 pv = *(const float4*)(pe + (long)s*512 + n_base);
    ushort4 ob;
    ob.x = f2bf(acc[r][0] + bias[n_base+0] + pv.x);
    ob.y = f2bf(acc[r][1] + bias[n_base+1] + pv.y);
    ob.z = f2bf(acc[r][2] + bias[n_base+2] + pv.z);
    ob.w = f2bf(acc[r][3] + bias[n_base+3] + pv.w);
    *(ushort4*)(Cb + (long)m*N + n_base) = ob;
  }
}

// fp32 -> bf16 cast of all 4 weight tensors in one dispatch
#define N4_QKV (NLAYER*3*D_MODEL*D_MODEL/4)
#define N4_WO  (NLAYER*D_MODEL*D_MODEL/4)
#define N4_W1  (NLAYER*D_FF*D_MODEL/4)
#define N4_W2  (NLAYER*D_MODEL*D_FF/4)
__global__ __launch_bounds__(256)
void cvt_all(const float* __restrict__ wq, const float* __restrict__ wo,
             const float* __restrict__ w1, const float* __restrict__ w2,
             unsigned short* __restrict__ oq, unsigned short* __restrict__ oo,
             unsigned short* __restrict__ o1, unsigned short* __restrict__ o2)
{
  int i = blockIdx.x*256 + threadIdx.x;
  const float* src; unsigned short* dst; int off;
  if (i < N4_QKV)                          { src = wq; dst = oq; off = i; }
  else if (i < N4_QKV + N4_WO)             { src = wo; dst = oo; off = i - N4_QKV; }
  else if (i < N4_QKV + N4_WO + N4_W1)     { src = w1; dst = o1; off = i - N4_QKV - N4_WO; }
  else if (i < N4_QKV + N4_WO + N4_W1 + N4_W2) { src = w2; dst = o2; off = i - N4_QKV - N4_WO - N4_W1; }
  else return;
  float4 v = ((const float4*)src)[off];
  ushort4 o;
  o.x = f2bf(v.x); o.y = f2bf(v.y); o.z = f2bf(v.z); o.w = f2bf(v.w);
  ((ushort4*)dst)[off] = o;
}

__global__ __launch_bounds__(256)
void out_init(float* __restrict__ out, const int* __restrict__ lens)
{
  int i = blockIdx.x*256 + threadIdx.x;
  if (i < 8192) out[i] = 0.f;
  else if (i < 8192 + 16) out[i] = (float)lens[i - 8192];
}

// masked mean pool over bf16 h
__global__ __launch_bounds__(256)
void pool_kernel(const unsigned short* __restrict__ hb,
                 const int* __restrict__ lens, float* __restrict__ out)
{
  const int b = blockIdx.y;
  const int s0 = blockIdx.x * 64;
  const int len = lens[b];
  if (s0 >= len) return;
  const int send = min(s0 + 64, len);
  const int tid = threadIdx.x;       // handles cols 2*tid, 2*tid+1
  float acc0 = 0.f, acc1 = 0.f;
  for (int s = s0; s < send; s++) {
    const unsigned* row = (const unsigned*)(hb + (long)(b*512 + s)*512);
    unsigned v = row[tid];
    acc0 += bf2f((unsigned short)(v & 0xFFFF));
    acc1 += bf2f((unsigned short)(v >> 16));
  }
  const float inv = 1.0f / (float)len;
  atomicAdd(out + b*512 + 2*tid,     acc0 * inv);
  atomicAdd(out + b*512 + 2*tid + 1, acc1 * inv);
}

// ---------------------------------------------------------------------------
extern "C" void kernel_launch(void* const* d_in, const int* in_sizes, int n_in,
                              void* d_out, int out_size, void* d_ws, size_t ws_size,
                              hipStream_t stream)
{
  const float* x    = (const float*)d_in[0];
  const int*   lens = (const int*)  d_in[1];
  const float* We   = (const float*)d_in[2];
  const float* be   = (const float*)d_in[3];
  const float* Wqkv = (const float*)d_in[4];
  const float* bqkv = (const float*)d_in[5];
  const float* Wo   = (const float*)d_in[6];
  const float* bo   = (const float*)d_in[7];
  const float* ln1g = (const float*)d_in[8];
  const float* ln1b = (const float*)d_in[9];
  const float* W1   = (const float*)d_in[10];
  const float* b1   = (const float*)d_in[11];
  const float* W2   = (const float*)d_in[12];
  const float* b2   = (const float*)d_in[13];
  const float* ln2g = (const float*)d_in[14];
  const float* ln2b = (const float*)d_in[15];
  float* out = (float*)d_out;

  // Workspace layout
  const long TOK_D = (long)NTOK * D_MODEL;              // 4,194,304
  float* ws  = (float*)d_ws;
  float* pe  = ws;                                      // fp32 [512,512] (1 MB)
  unsigned short* us    = (unsigned short*)(ws + 1*TOK_D);
  unsigned short* h_b   = us;                           // bf16 [8192,512]
  unsigned short* ctx_b = us + 1*TOK_D;
  unsigned short* q_b   = us + 2*TOK_D;                 // [bh][s][64] (pre-scaled 1/8)
  unsigned short* k_b   = us + 3*TOK_D;                 // [bh][s][64]
  unsigned short* vt_b  = us + 4*TOK_D;                 // [bh][d][s]
  unsigned short* ff_b  = us + 5*TOK_D;                 // bf16 [8192,2048]
  unsigned short* wq_b  = us + 9*TOK_D;
  unsigned short* wo_b  = wq_b + (long)NLAYER*3*D_MODEL*D_MODEL;
  unsigned short* w1_b  = wo_b + (long)NLAYER*D_MODEL*D_MODEL;
  unsigned short* w2_b  = w1_b + (long)NLAYER*D_FF*D_MODEL;
  unsigned short* part  = w2_b + (long)NLAYER*D_MODEL*D_FF;  // [<=4][8192][512]

  const dim3 blk(256);

  // 0) weight casts + PE table
  {
    const int n4tot = N4_QKV + N4_WO + N4_W1 + N4_W2;
    cvt_all<<<dim3((n4tot+255)/256), blk, 0, stream>>>(
        Wqkv, Wo, W1, W2, wq_b, wo_b, w1_b, w2_b);
    pe_kernel<<<dim3(512*512/256), blk, 0, stream>>>(pe);
  }

  // 1) embedding + posenc -> h_b (bf16)
  gemm_embed<<<dim3(D_MODEL/64, NTOK/128), blk, 0, stream>>>(
      x, We, be, pe, h_b, 80, D_MODEL);

  for (int l = 0; l < NLAYER; l++) {
    const unsigned short* wq_l = wq_b + (long)l * 3*D_MODEL * D_MODEL;
    const unsigned short* wo_l = wo_b + (long)l * D_MODEL * D_MODEL;
    const unsigned short* w1_l = w1_b + (long)l * D_FF * D_MODEL;
    const unsigned short* w2_l = w2_b + (long)l * D_MODEL * D_FF;
    const float* bqkv_l = bqkv + (long)l * 3*D_MODEL;
    const float* bo_l   = bo   + (long)l * D_MODEL;
    const float* b1_l   = b1   + (long)l * D_FF;
    const float* b2_l   = b2   + (long)l * D_MODEL;

    // q,k = h*Wqk^T + b -> [bh][s][64], q pre-scaled 1/8
    gemm_mfma<MODE_QK><<<dim3(2*D_MODEL/128, NTOK/128), blk, 0, stream>>>(
        h_b, wq_l, bqkv_l, nullptr, q_b, k_b, lens, D_MODEL, D_MODEL, 2*D_MODEL);

    // v^T = Wv*h^T + bv -> [bh][d][s]
    gemm_mfma<MODE_VT><<<dim3(NTOK/128, D_MODEL/128), blk, 0, stream>>>(
        wq_l + (long)2*D_MODEL*D_MODEL, h_b, bqkv_l + 2*D_MODEL, vt_b,
        nullptr, nullptr, lens, D_MODEL, D_MODEL, NTOK);

    // attention -> ctx_b
    attn_mfma<<<dim3(NHEAD*BATCH, SMAX/64), blk, 0, stream>>>(
        q_b, k_b, vt_b, lens, ctx_b);

    // Wo partials (split-K x2) + fused reduce+resid+LN1
    gemm_mfma<MODE_PART><<<dim3(D_MODEL/128, NTOK/128, 2), blk, 0, stream>>>(
        ctx_b, wo_l, nullptr, part, nullptr, nullptr, lens, D_MODEL, D_MODEL/2, D_MODEL);
    reduce_ln<2><<<dim3(NTOK), dim3(128), 0, stream>>>(
        part, bo_l, ln1g + l*D_MODEL, ln1b + l*D_MODEL, h_b, lens);

    // ff_b = bf16(relu(h*W1^T + b1))
    gemm_mfma<MODE_RELU><<<dim3(D_FF/128, NTOK/128), blk, 0, stream>>>(
        h_b, w1_l, b1_l, ff_b, nullptr, nullptr, lens, D_MODEL, D_MODEL, D_FF);

    // FF2 partials (split-K x4) + fused reduce+resid+LN2
    gemm_mfma<MODE_PART><<<dim3(D_MODEL/128, NTOK/128, 4), blk, 0, stream>>>(
        ff_b, w2_l, nullptr, part, nullptr, nullptr, lens, D_FF, D_FF/4, D_MODEL);
    reduce_ln<4><<<dim3(NTOK), dim3(128), 0, stream>>>(
        part, b2_l, ln2g + l*D_MODEL, ln2b + l*D_MODEL, h_b, lens);
  }

  // 3) masked mean pool + lens output
  out_init<<<dim3((8192 + 16 + 255) / 256), blk, 0, stream>>>(out, lens);
  pool_kernel<<<dim3(SMAX/64, BATCH), blk, 0, stream>>>(h_b, lens, out);
}

// Round 10
// 637.977 us; speedup vs baseline: 1.3357x; 1.1847x over previous
//
#include <hip/hip_runtime.h>
#include <math.h>

// Problem constants
#define D_MODEL 512
#define NHEAD   8
#define DH      64
#define D_FF    2048
#define BATCH   16
#define SMAX    512
#define NTOK    (BATCH*SMAX)   // 8192
#define NLAYER  4

constexpr int MODE_QK   = 1;  // bf16 q (pre-scaled 1/8) / k rows [bh][s][64]
constexpr int MODE_VT   = 2;  // bf16 vt [bh][d][s], bias along m
constexpr int MODE_RELU = 3;  // fp8 ff = relu(A*B^T + bias), row-major
constexpr int MODE_PART = 4;  // bf16 partial [z][tok][512]

typedef __attribute__((ext_vector_type(8))) __bf16 bf16x8;
typedef __attribute__((ext_vector_type(4))) float  f32x4;
typedef unsigned char u8;

#define WSCALE_INV 0.03125f   // weights stored fp8 x32

__device__ __forceinline__ unsigned short f2bf(float f) {
  union { float f; unsigned u; } v; v.f = f;
  unsigned r = v.u + 0x7FFFu + ((v.u >> 16) & 1u);
  return (unsigned short)(r >> 16);
}
__device__ __forceinline__ float bf2f(unsigned short u) {
  union { unsigned u; float f; } v; v.u = ((unsigned)u) << 16; return v.f;
}
// pack 4 floats -> 4 fp8 e4m3 in one int
__device__ __forceinline__ int pk4(float a, float b, float c, float d) {
  int t = __builtin_amdgcn_cvt_pk_fp8_f32(a, b, 0, false);
  t = __builtin_amdgcn_cvt_pk_fp8_f32(c, d, t, true);
  return t;
}

__device__ __forceinline__ void gl_lds16(const unsigned short* g, unsigned short* l) {
  __builtin_amdgcn_global_load_lds(
      (const __attribute__((address_space(1))) unsigned int*)g,
      (__attribute__((address_space(3)))       unsigned int*)l, 16, 0, 0);
}
__device__ __forceinline__ void gl_lds16b(const u8* g, u8* l) {
  __builtin_amdgcn_global_load_lds(
      (const __attribute__((address_space(1))) unsigned int*)g,
      (__attribute__((address_space(3)))       unsigned int*)l, 16, 0, 0);
}

// fp8 tile fragment address: [half][row&63][chunk^((row>>1)&3)][8B of quad&1]
__device__ __forceinline__ const long* fragp(const u8* base, int row, int ks, int quad) {
  const int addr = ((row >> 6) << 12) + ((row & 63) << 6)
                 + (((((ks << 1) | (quad >> 1)) ^ ((row >> 1) & 3)) << 4))
                 + ((quad & 1) << 3);
  return (const long*)(base + addr);
}

// ---------------------------------------------------------------------------
// fp8 MFMA GEMM: 128x128 tile, BK=64, 3-stage vmcnt(4) pipeline, 256 thr.
// A,B fp8 e4m3 (B = weights, x32 scaled except VT's B=activations... see modes:
//   QK/RELU/PART: A=activation (unscaled), B=weight(x32)  -> acc*WSCALE_INV
//   VT:           A=weight(x32),           B=activation   -> acc*WSCALE_INV
// XOR-chunk swizzle keeps global_load_lds legal and b64 frag reads conflict-min.
// ---------------------------------------------------------------------------
template<int MODE>
__global__ __launch_bounds__(256)
void gemm_fp8(const u8* __restrict__ A, const u8* __restrict__ Bw,
              const float* __restrict__ bias, u8* __restrict__ C8,
              unsigned short* __restrict__ Cb,
              unsigned short* __restrict__ qd, unsigned short* __restrict__ kd,
              const int* __restrict__ lens, int K, int CK, int N)
{
  const int lin = blockIdx.x + gridDim.x*(blockIdx.y + gridDim.y*blockIdx.z);
  int m0, n0, kz = 0;
  if (MODE == MODE_VT) {
    n0 = (lin % gridDim.x) * 128;
    m0 = (lin / gridDim.x) * 128;
  } else {
    m0 = (lin % gridDim.y) * 128;
    const int rest = lin / gridDim.y;
    n0 = (rest % gridDim.x) * 128;
    kz = rest / gridDim.x;
  }
  if (MODE == MODE_VT) { if ((n0 & 511) >= lens[n0 >> 9]) return; }
  else                 { if ((m0 & 511) >= lens[m0 >> 9]) return; }

  __shared__ __attribute__((aligned(16))) u8 As[3][8192];
  __shared__ __attribute__((aligned(16))) u8 Bs[3][8192];
  const int tid  = threadIdx.x;
  const int lane = tid & 63;
  const int w    = tid >> 6;
  const int wm   = (w & 1) * 64;
  const int wn   = (w >> 1) * 64;
  const int l15  = lane & 15, quad = lane >> 4;

  f32x4 acc[4][4] = {};

  // staging: row = tid>>2 (0..63), chunk XOR-swizzled by (row>>1)&3
  const int sr  = tid >> 2;
  const int sch = ((tid & 3) ^ ((tid >> 3) & 3)) * 16;
  const u8* Ag = A  + (long)(m0 + sr) * K + kz*CK + sch;
  const u8* Bg = Bw + (long)(n0 + sr) * K + kz*CK + sch;
  const long rowskip = (long)64 * K;
  const int t16 = tid * 16;
  const int niter = CK >> 6;

  auto stage = [&](int t, int bix) {
    const u8* a_ = Ag + t*64;
    const u8* b_ = Bg + t*64;
    gl_lds16b(a_,           &As[bix][t16]);
    gl_lds16b(a_ + rowskip, &As[bix][4096 + t16]);
    gl_lds16b(b_,           &Bs[bix][t16]);
    gl_lds16b(b_ + rowskip, &Bs[bix][4096 + t16]);
  };

  stage(0, 0);
  stage(1, 1);

  for (int it = 0; it < niter; ++it) {
    if (it + 1 < niter)
      asm volatile("s_waitcnt vmcnt(4)\n\ts_barrier" ::: "memory");
    else
      asm volatile("s_waitcnt vmcnt(0)\n\ts_barrier" ::: "memory");
    if (it + 2 < niter) stage(it + 2, (it + 2) % 3);

    const int cur = it % 3;
#pragma unroll
    for (int ks = 0; ks < 2; ks++) {
      long af[4], bfv[4];
#pragma unroll
      for (int i = 0; i < 4; i++)
        af[i] = *fragp(&As[cur][0], wm + i*16 + l15, ks, quad);
#pragma unroll
      for (int j = 0; j < 4; j++)
        bfv[j] = *fragp(&Bs[cur][0], wn + j*16 + l15, ks, quad);
#pragma unroll
      for (int i = 0; i < 4; i++)
#pragma unroll
        for (int j = 0; j < 4; j++)
          acc[i][j] = __builtin_amdgcn_mfma_f32_16x16x32_fp8_fp8(af[i], bfv[j], acc[i][j], 0, 0, 0);
    }
  }

  // ---- epilogue ----
  __syncthreads();
  const int rr8 = lane >> 3, ch8 = lane & 7;

  if (MODE == MODE_RELU) {
    // float bounce -> fp8 pack -> 16B stores
    float* epf = (float*)&As[0][0] + w * 1088;   // 16 rows x 68 floats
#pragma unroll
    for (int i = 0; i < 4; i++) {
#pragma unroll
      for (int j = 0; j < 4; j++) {
        const float cbv = bias[n0 + wn + j*16 + l15];
#pragma unroll
        for (int r = 0; r < 4; r++)
          epf[(quad*4 + r)*68 + j*16 + l15] = fmaxf(acc[i][j][r]*WSCALE_INV + cbv, 0.f);
      }
      asm volatile("s_waitcnt lgkmcnt(0)" ::: "memory");
      const int row = lane >> 2, c16 = (lane & 3) * 16;
      const float* rp = epf + row*68 + c16;
      f32x4 f0 = *(const f32x4*)(rp + 0);
      f32x4 f1 = *(const f32x4*)(rp + 4);
      f32x4 f2 = *(const f32x4*)(rp + 8);
      f32x4 f3 = *(const f32x4*)(rp + 12);
      int4 o;
      o.x = pk4(f0.x, f0.y, f0.z, f0.w);
      o.y = pk4(f1.x, f1.y, f1.z, f1.w);
      o.z = pk4(f2.x, f2.y, f2.z, f2.w);
      o.w = pk4(f3.x, f3.y, f3.z, f3.w);
      const int mrow = m0 + wm + i*16 + row;
      *(int4*)&C8[(long)mrow*N + n0 + wn + c16] = o;
      asm volatile("s_waitcnt lgkmcnt(0)" ::: "memory");
    }
  } else {
    // bf16 bounce (QK / VT / PART)
    unsigned short* epi = (unsigned short*)&As[0][0] + w * 1152;
    const bool isq = (MODE == MODE_QK) && (((n0 + wn) >> 9) == 0);
#pragma unroll
    for (int i = 0; i < 4; i++) {
      float rbv[4];
      if (MODE == MODE_VT) {
#pragma unroll
        for (int r = 0; r < 4; r++) rbv[r] = bias[m0 + wm + i*16 + quad*4 + r];
      }
#pragma unroll
      for (int j = 0; j < 4; j++) {
        float cbv = 0.f;
        if (MODE == MODE_QK) cbv = bias[n0 + wn + j*16 + l15];
#pragma unroll
        for (int r = 0; r < 4; r++) {
          float v = acc[i][j][r] * WSCALE_INV;
          if (MODE == MODE_QK)   { v += cbv; if (isq) v *= 0.125f; }
          if (MODE == MODE_VT)   v += rbv[r];
          epi[(quad*4 + r)*72 + j*16 + l15] = f2bf(v);
        }
      }
      asm volatile("s_waitcnt lgkmcnt(0)" ::: "memory");
#pragma unroll
      for (int rs = 0; rs < 2; rs++) {
        const int row  = rs*8 + rr8;
        const int mrow = m0 + wm + i*16 + row;
        bf16x8 val = *(const bf16x8*)&epi[row*72 + ch8*8];
        if (MODE == MODE_PART) {
          *(bf16x8*)&Cb[((long)kz*NTOK + mrow)*N + n0 + wn + ch8*8] = val;
        } else if (MODE == MODE_QK) {
          const int nb    = n0 + wn;
          const int which = nb >> 9;
          const int head  = (nb >> 6) & 7;
          unsigned short* dst = which ? kd : qd;
          const int bh = (mrow >> 9)*8 + head;
          *(bf16x8*)&dst[((long)(bh*512 + (mrow & 511)))*64 + ch8*8] = val;
        } else {  // MODE_VT
          const int head = mrow >> 6, d = mrow & 63;
          const int tok  = n0 + wn + ch8*8;
          const int b    = tok >> 9;
          *(bf16x8*)&Cb[((long)((b*8 + head)*64 + d))*512 + (tok & 511)] = val;
        }
      }
      asm volatile("s_waitcnt lgkmcnt(0)" ::: "memory");
    }
  }
}

// ---------------------------------------------------------------------------
// Fused split-K reduce + bias + fp8 residual + LayerNorm -> fp8 h.
// ---------------------------------------------------------------------------
template<int KS>
__global__ __launch_bounds__(128)
void reduce_ln(const unsigned short* __restrict__ part,
               const float* __restrict__ bias,
               const float* __restrict__ g, const float* __restrict__ bb,
               u8* __restrict__ h8, const int* __restrict__ lens)
{
  const int row = blockIdx.x, tid = threadIdx.x;
  if ((row & 511) >= lens[row >> 9]) return;
  const int hv = ((const int*)(h8 + (long)row*512))[tid];
  float4 bs = ((const float4*)bias)[tid];
  float v0 = __builtin_amdgcn_cvt_f32_fp8(hv, 0) + bs.x;
  float v1 = __builtin_amdgcn_cvt_f32_fp8(hv, 1) + bs.y;
  float v2 = __builtin_amdgcn_cvt_f32_fp8(hv, 2) + bs.z;
  float v3 = __builtin_amdgcn_cvt_f32_fp8(hv, 3) + bs.w;
#pragma unroll
  for (int z = 0; z < KS; z++) {
    ushort4 p = ((const ushort4*)(part + ((long)z*NTOK + row)*512))[tid];
    v0 += bf2f(p.x); v1 += bf2f(p.y); v2 += bf2f(p.z); v3 += bf2f(p.w);
  }
  float s  = v0 + v1 + v2 + v3;
  float s2 = v0*v0 + v1*v1 + v2*v2 + v3*v3;
#pragma unroll
  for (int off = 1; off < 64; off <<= 1) {
    s  += __shfl_xor(s, off);
    s2 += __shfl_xor(s2, off);
  }
  __shared__ float rb[4];
  if ((tid & 63) == 0) { rb[(tid>>6)*2] = s; rb[(tid>>6)*2+1] = s2; }
  __syncthreads();
  s = rb[0] + rb[2]; s2 = rb[1] + rb[3];
  const float mean = s * (1.f/512.f);
  const float var  = fmaxf(s2 * (1.f/512.f) - mean*mean, 0.f);
  const float rstd = rsqrtf(var + 1e-5f);
  const int e = tid*4;
  const float o0 = (v0-mean)*rstd*g[e+0] + bb[e+0];
  const float o1 = (v1-mean)*rstd*g[e+1] + bb[e+1];
  const float o2 = (v2-mean)*rstd*g[e+2] + bb[e+2];
  const float o3 = (v3-mean)*rstd*g[e+3] + bb[e+3];
  ((int*)(h8 + (long)row*512))[tid] = pk4(o0, o1, o2, o3);
}

// ---------------------------------------------------------------------------
// MFMA flash attention (bf16), grid (bh, qt); ctx output packed fp8.
// ---------------------------------------------------------------------------
__global__ __launch_bounds__(256)
void attn_mfma(const unsigned short* __restrict__ qg,
               const unsigned short* __restrict__ kb,
               const unsigned short* __restrict__ vtb,
               const int* __restrict__ lens,
               u8* __restrict__ ctx8)
{
  const int bh = blockIdx.x, qt = blockIdx.y;
  const int b = bh >> 3, hh = bh & 7;
  const int len = lens[b];
  if (qt*64 >= len) return;

  __shared__ __attribute__((aligned(16))) u8 smem[41984];
  unsigned short* Ks0 = (unsigned short*)smem;              // [2][4096]
  unsigned short* Vts0 = (unsigned short*)(smem + 16384);   // [2][4096]
  unsigned short* Ps  = (unsigned short*)(smem + 32768);    // 4*16*72
  const int tid = threadIdx.x;
  const int w = tid >> 6, lane = tid & 63, l15 = lane & 15, quad = lane >> 4;
  const int t8 = tid * 8;

  const int srow = tid >> 2;
  const int s8   = (tid & 3) * 8;
  const unsigned short* Kbase = kb  + ((long)(bh*512 + srow))*64 + s8;
  const unsigned short* Vbase = vtb + ((long)(bh*64 + srow))*512 + s8;

  const unsigned short* qrow = qg + ((long)(bh*512 + qt*64 + w*16 + l15))*64;
  const bf16x8 qf0 = *(const bf16x8*)(qrow + quad*8);
  const bf16x8 qf1 = *(const bf16x8*)(qrow + 32 + quad*8);

  f32x4 O[4] = {};
  float mrow[4] = {-1e30f,-1e30f,-1e30f,-1e30f};
  float lrow[4] = {0.f,0.f,0.f,0.f};
  unsigned short* Pw = &Ps[w*16*72];
  const int ntiles = (len + 63) >> 6;

  {
    gl_lds16(Kbase,      &Ks0[t8]);
    gl_lds16(Kbase + 32, &Ks0[2048 + t8]);
    gl_lds16(Vbase,      &Vts0[t8]);
    gl_lds16(Vbase + 32, &Vts0[2048 + t8]);
  }

  for (int kt = 0; kt < ntiles; kt++) {
    const int cur = kt & 1;
    unsigned short* Kc  = Ks0  + cur*4096;
    unsigned short* Vc  = Vts0 + cur*4096;
    __syncthreads();
    if (kt + 1 < ntiles) {
      const unsigned short* Kg = Kbase + (long)(kt+1)*64*64;
      const unsigned short* Vg = Vbase + (long)(kt+1)*64;
      unsigned short* Kn = Ks0  + (cur^1)*4096;
      unsigned short* Vn = Vts0 + (cur^1)*4096;
      gl_lds16(Kg,      &Kn[t8]);
      gl_lds16(Kg + 32, &Kn[2048 + t8]);
      gl_lds16(Vg,      &Vn[t8]);
      gl_lds16(Vg + 32, &Vn[2048 + t8]);
    }

    f32x4 sc[4];
#pragma unroll
    for (int ks = 0; ks < 4; ks++) {
      bf16x8 kf0 = *(const bf16x8*)&Kc[       (ks*16 + l15)*32 + quad*8];
      bf16x8 kf1 = *(const bf16x8*)&Kc[2048 + (ks*16 + l15)*32 + quad*8];
      f32x4 z = {};
      z = __builtin_amdgcn_mfma_f32_16x16x32_bf16(qf0, kf0, z, 0, 0, 0);
      sc[ks] = __builtin_amdgcn_mfma_f32_16x16x32_bf16(qf1, kf1, z, 0, 0, 0);
    }

    if (kt*64 + 64 > len) {
#pragma unroll
      for (int ks = 0; ks < 4; ks++) {
        const bool valid = (kt*64 + ks*16 + l15) < len;
#pragma unroll
        for (int r = 0; r < 4; r++)
          sc[ks][r] = valid ? sc[ks][r] : -1e30f;
      }
    }

    float pv[4][4];
#pragma unroll
    for (int r = 0; r < 4; r++) {
      float mx = fmaxf(fmaxf(sc[0][r], sc[1][r]), fmaxf(sc[2][r], sc[3][r]));
      mx = fmaxf(mx, __shfl_xor(mx, 1));
      mx = fmaxf(mx, __shfl_xor(mx, 2));
      mx = fmaxf(mx, __shfl_xor(mx, 4));
      mx = fmaxf(mx, __shfl_xor(mx, 8));
      const float newm  = fmaxf(mrow[r], mx);
      const float alpha = __expf(mrow[r] - newm);
      float ps = 0.f;
#pragma unroll
      for (int ks = 0; ks < 4; ks++) { pv[ks][r] = __expf(sc[ks][r] - newm); ps += pv[ks][r]; }
      ps += __shfl_xor(ps, 1); ps += __shfl_xor(ps, 2);
      ps += __shfl_xor(ps, 4); ps += __shfl_xor(ps, 8);
      lrow[r] = lrow[r]*alpha + ps;
      mrow[r] = newm;
#pragma unroll
      for (int d = 0; d < 4; d++) O[d][r] *= alpha;
    }

#pragma unroll
    for (int ks = 0; ks < 4; ks++)
#pragma unroll
      for (int r = 0; r < 4; r++)
        Pw[(quad*4 + r)*72 + ks*16 + l15] = f2bf(pv[ks][r]);
    asm volatile("s_waitcnt lgkmcnt(0)" ::: "memory");

    const bf16x8 pa0 = *(const bf16x8*)&Pw[l15*72 + quad*8];
    const bf16x8 pa1 = *(const bf16x8*)&Pw[l15*72 + 32 + quad*8];
#pragma unroll
    for (int d = 0; d < 4; d++) {
      bf16x8 vf0 = *(const bf16x8*)&Vc[       (d*16 + l15)*32 + quad*8];
      bf16x8 vf1 = *(const bf16x8*)&Vc[2048 + (d*16 + l15)*32 + quad*8];
      O[d] = __builtin_amdgcn_mfma_f32_16x16x32_bf16(pa0, vf0, O[d], 0, 0, 0);
      O[d] = __builtin_amdgcn_mfma_f32_16x16x32_bf16(pa1, vf1, O[d], 0, 0, 0);
    }
  }

  // ctx: float bounce (reuses Ks/Vts area) -> fp8 pack -> 16B stores
  __syncthreads();
  float* epf = (float*)smem + w * 1088;   // 16 x 68 floats per wave
#pragma unroll
  for (int r = 0; r < 4; r++) {
    const float inv = 1.f / lrow[r];
#pragma unroll
    for (int d = 0; d < 4; d++)
      epf[(quad*4 + r)*68 + d*16 + l15] = O[d][r] * inv;
  }
  asm volatile("s_waitcnt lgkmcnt(0)" ::: "memory");
  {
    const int row = lane >> 2, c16 = (lane & 3) * 16;
    const float* rp = epf + row*68 + c16;
    f32x4 f0 = *(const f32x4*)(rp + 0);
    f32x4 f1 = *(const f32x4*)(rp + 4);
    f32x4 f2 = *(const f32x4*)(rp + 8);
    f32x4 f3 = *(const f32x4*)(rp + 12);
    int4 o;
    o.x = pk4(f0.x, f0.y, f0.z, f0.w);
    o.y = pk4(f1.x, f1.y, f1.z, f1.w);
    o.z = pk4(f2.x, f2.y, f2.z, f2.w);
    o.w = pk4(f3.x, f3.y, f3.z, f3.w);
    const long gaddr = (long)(b*512 + qt*64 + w*16 + row)*512 + hh*64 + c16;
    *(int4*)&ctx8[gaddr] = o;
  }
}

// ---------------------------------------------------------------------------
// PE table (once per launch)
// ---------------------------------------------------------------------------
__global__ __launch_bounds__(256)
void pe_kernel(float* __restrict__ pe)
{
  const int i = blockIdx.x*256 + threadIdx.x;
  const int s = i >> 9, e = i & 511;
  const float dv  = __expf((float)(e & ~1) * (-9.210340371976184f / 512.0f));
  const float ang = (float)s * dv;
  pe[i] = (e & 1) ? cosf(ang) : sinf(ang);
}

// ---------------------------------------------------------------------------
// fp32 embedding GEMM (K=80): h8 = fp8(x*We^T + be + pe[s]).
// ---------------------------------------------------------------------------
__global__ __launch_bounds__(256)
void gemm_embed(const float* __restrict__ A, const float* __restrict__ Bm,
                const float* __restrict__ bias, const float* __restrict__ pe,
                u8* __restrict__ C8, int K, int N)
{
  __shared__ float As[8][132];
  __shared__ float Bs[8][68];
  const int tid = threadIdx.x;
  const int m0 = blockIdx.y * 128;
  const int n0 = blockIdx.x * 64;
  const int tx = tid & 15, ty = tid >> 4;
  const int a_k = tid & 7, a_m = tid >> 3;

  float acc[8][4] = {};
  const float* Ag = A  + (long)(m0 + a_m) * K + a_k;
  const float* Bg = Bm + (long)(n0 + a_m) * K + a_k;

  for (int k0 = 0; k0 < K; k0 += 8) {
#pragma unroll
    for (int i = 0; i < 4; i++)
      As[a_k][a_m + 32*i] = Ag[k0 + (long)32*i*K];
#pragma unroll
    for (int i = 0; i < 2; i++)
      Bs[a_k][a_m + 32*i] = Bg[k0 + (long)32*i*K];
    __syncthreads();
#pragma unroll
    for (int kk = 0; kk < 8; kk++) {
      float a[8], bv[4];
#pragma unroll
      for (int r = 0; r < 8; r++) a[r] = As[kk][ty*8 + r];
#pragma unroll
      for (int c = 0; c < 4; c++) bv[c] = Bs[kk][tx*4 + c];
#pragma unroll
      for (int r = 0; r < 8; r++)
#pragma unroll
        for (int c = 0; c < 4; c++)
          acc[r][c] += a[r] * bv[c];
    }
    __syncthreads();
  }

  const int n_base = n0 + tx*4;
#pragma unroll
  for (int r = 0; r < 8; r++) {
    int m = m0 + ty*8 + r;
    int s = m & 511;
    float4 pv = *(const float4*)(pe + (long)s*512 + n_base);
    int o = pk4(acc[r][0] + bias[n_base+0] + pv.x,
                acc[r][1] + bias[n_base+1] + pv.y,
                acc[r][2] + bias[n_base+2] + pv.z,
                acc[r][3] + bias[n_base+3] + pv.w);
    *(int*)(C8 + (long)m*N + n_base) = o;
  }
}

// fp32 -> fp8 (x32) cast of all 4 weight tensors in one dispatch
#define N4_QKV (NLAYER*3*D_MODEL*D_MODEL/4)
#define N4_WO  (NLAYER*D_MODEL*D_MODEL/4)
#define N4_W1  (NLAYER*D_FF*D_MODEL/4)
#define N4_W2  (NLAYER*D_MODEL*D_FF/4)
__global__ __launch_bounds__(256)
void cvt_all(const float* __restrict__ wq, const float* __restrict__ wo,
             const float* __restrict__ w1, const float* __restrict__ w2,
             u8* __restrict__ oq, u8* __restrict__ oo,
             u8* __restrict__ o1, u8* __restrict__ o2)
{
  int i = blockIdx.x*256 + threadIdx.x;
  const float* src; u8* dst; int off;
  if (i < N4_QKV)                          { src = wq; dst = oq; off = i; }
  else if (i < N4_QKV + N4_WO)             { src = wo; dst = oo; off = i - N4_QKV; }
  else if (i < N4_QKV + N4_WO + N4_W1)     { src = w1; dst = o1; off = i - N4_QKV - N4_WO; }
  else if (i < N4_QKV + N4_WO + N4_W1 + N4_W2) { src = w2; dst = o2; off = i - N4_QKV - N4_WO - N4_W1; }
  else return;
  float4 v = ((const float4*)src)[off];
  ((int*)dst)[off] = pk4(v.x*32.f, v.y*32.f, v.z*32.f, v.w*32.f);
}

__global__ __launch_bounds__(256)
void out_init(float* __restrict__ out, const int* __restrict__ lens)
{
  int i = blockIdx.x*256 + threadIdx.x;
  if (i < 8192) out[i] = 0.f;
  else if (i < 8192 + 16) out[i] = (float)lens[i - 8192];
}

// masked mean pool over fp8 h
__global__ __launch_bounds__(256)
void pool_kernel(const u8* __restrict__ h8,
                 const int* __restrict__ lens, float* __restrict__ out)
{
  const int b = blockIdx.y;
  const int s0 = blockIdx.x * 64;
  const int len = lens[b];
  if (s0 >= len) return;
  const int send = min(s0 + 64, len);
  const int tid = threadIdx.x;
  const int c = (tid & 127) * 4;     // 4 consecutive cols
  const int half = tid >> 7;
  float a0 = 0.f, a1 = 0.f, a2 = 0.f, a3 = 0.f;
  for (int s = s0 + half; s < send; s += 2) {
    const int v = *(const int*)(h8 + ((long)(b*512 + s))*512 + c);
    a0 += __builtin_amdgcn_cvt_f32_fp8(v, 0);
    a1 += __builtin_amdgcn_cvt_f32_fp8(v, 1);
    a2 += __builtin_amdgcn_cvt_f32_fp8(v, 2);
    a3 += __builtin_amdgcn_cvt_f32_fp8(v, 3);
  }
  const float inv = 1.0f / (float)len;
  atomicAdd(out + b*512 + c + 0, a0 * inv);
  atomicAdd(out + b*512 + c + 1, a1 * inv);
  atomicAdd(out + b*512 + c + 2, a2 * inv);
  atomicAdd(out + b*512 + c + 3, a3 * inv);
}

// ---------------------------------------------------------------------------
extern "C" void kernel_launch(void* const* d_in, const int* in_sizes, int n_in,
                              void* d_out, int out_size, void* d_ws, size_t ws_size,
                              hipStream_t stream)
{
  const float* x    = (const float*)d_in[0];
  const int*   lens = (const int*)  d_in[1];
  const float* We   = (const float*)d_in[2];
  const float* be   = (const float*)d_in[3];
  const float* Wqkv = (const float*)d_in[4];
  const float* bqkv = (const float*)d_in[5];
  const float* Wo   = (const float*)d_in[6];
  const float* bo   = (const float*)d_in[7];
  const float* ln1g = (const float*)d_in[8];
  const float* ln1b = (const float*)d_in[9];
  const float* W1   = (const float*)d_in[10];
  const float* b1   = (const float*)d_in[11];
  const float* W2   = (const float*)d_in[12];
  const float* b2   = (const float*)d_in[13];
  const float* ln2g = (const float*)d_in[14];
  const float* ln2b = (const float*)d_in[15];
  float* out = (float*)d_out;

  // Workspace layout (bytes)
  const long TOK_D = (long)NTOK * D_MODEL;              // 4,194,304
  u8* base = (u8*)d_ws;
  float* pe = (float*)base;                             // 1 MB fp32
  u8* h8    = base + 4*TOK_D;                           // fp8 [8192,512]
  u8* ctx8  = h8   + TOK_D;                             // fp8 [8192,512]
  u8* ff8   = ctx8 + TOK_D;                             // fp8 [8192,2048]
  unsigned short* q_b  = (unsigned short*)(ff8 + 4*TOK_D);  // bf16 [bh][s][64]
  unsigned short* k_b  = q_b + TOK_D;
  unsigned short* vt_b = k_b + TOK_D;                   // bf16 [bh][d][s]
  unsigned short* part = vt_b + TOK_D;                  // bf16 [4][8192][512]
  u8* wq8 = (u8*)(part + 4*TOK_D);
  u8* wo8 = wq8 + (long)NLAYER*3*D_MODEL*D_MODEL;
  u8* w18 = wo8 + (long)NLAYER*D_MODEL*D_MODEL;
  u8* w28 = w18 + (long)NLAYER*D_FF*D_MODEL;

  const dim3 blk(256);

  // 0) weight casts (fp8 x32) + PE table
  {
    const int n4tot = N4_QKV + N4_WO + N4_W1 + N4_W2;
    cvt_all<<<dim3((n4tot+255)/256), blk, 0, stream>>>(
        Wqkv, Wo, W1, W2, wq8, wo8, w18, w28);
    pe_kernel<<<dim3(512*512/256), blk, 0, stream>>>(pe);
  }

  // 1) embedding + posenc -> h8 (fp8)
  gemm_embed<<<dim3(D_MODEL/64, NTOK/128), blk, 0, stream>>>(
      x, We, be, pe, h8, 80, D_MODEL);

  for (int l = 0; l < NLAYER; l++) {
    const u8* wq_l = wq8 + (long)l * 3*D_MODEL * D_MODEL;
    const u8* wo_l = wo8 + (long)l * D_MODEL * D_MODEL;
    const u8* w1_l = w18 + (long)l * D_FF * D_MODEL;
    const u8* w2_l = w28 + (long)l * D_MODEL * D_FF;
    const float* bqkv_l = bqkv + (long)l * 3*D_MODEL;
    const float* bo_l   = bo   + (long)l * D_MODEL;
    const float* b1_l   = b1   + (long)l * D_FF;
    const float* b2_l   = b2   + (long)l * D_MODEL;

    // q,k = h*Wqk^T + b -> bf16 [bh][s][64], q pre-scaled 1/8
    gemm_fp8<MODE_QK><<<dim3(2*D_MODEL/128, NTOK/128), blk, 0, stream>>>(
        h8, wq_l, bqkv_l, nullptr, nullptr, q_b, k_b, lens, D_MODEL, D_MODEL, 2*D_MODEL);

    // v^T = Wv*h^T + bv -> bf16 [bh][d][s]
    gemm_fp8<MODE_VT><<<dim3(NTOK/128, D_MODEL/128), blk, 0, stream>>>(
        wq_l + (long)2*D_MODEL*D_MODEL, h8, bqkv_l + 2*D_MODEL, nullptr, vt_b,
        nullptr, nullptr, lens, D_MODEL, D_MODEL, NTOK);

    // attention -> ctx8 (fp8)
    attn_mfma<<<dim3(NHEAD*BATCH, SMAX/64), blk, 0, stream>>>(
        q_b, k_b, vt_b, lens, ctx8);

    // Wo partials (split-K x2) + fused reduce+resid+LN1
    gemm_fp8<MODE_PART><<<dim3(D_MODEL/128, NTOK/128, 2), blk, 0, stream>>>(
        ctx8, wo_l, nullptr, nullptr, part, nullptr, nullptr, lens,
        D_MODEL, D_MODEL/2, D_MODEL);
    reduce_ln<2><<<dim3(NTOK), dim3(128), 0, stream>>>(
        part, bo_l, ln1g + l*D_MODEL, ln1b + l*D_MODEL, h8, lens);

    // ff8 = fp8(relu(h*W1^T + b1))
    gemm_fp8<MODE_RELU><<<dim3(D_FF/128, NTOK/128), blk, 0, stream>>>(
        h8, w1_l, b1_l, ff8, nullptr, nullptr, nullptr, lens, D_MODEL, D_MODEL, D_FF);

    // FF2 partials (split-K x4) + fused reduce+resid+LN2
    gemm_fp8<MODE_PART><<<dim3(D_MODEL/128, NTOK/128, 4), blk, 0, stream>>>(
        ff8, w2_l, nullptr, nullptr, part, nullptr, nullptr, lens,
        D_FF, D_FF/4, D_MODEL);
    reduce_ln<4><<<dim3(NTOK), dim3(128), 0, stream>>>(
        part, b2_l, ln2g + l*D_MODEL, ln2b + l*D_MODEL, h8, lens);
  }

  // 3) masked mean pool + lens output
  out_init<<<dim3((8192 + 16 + 255) / 256), blk, 0, stream>>>(out, lens);
  pool_kernel<<<dim3(SMAX/64, BATCH), blk, 0, stream>>>(h8, lens, out);
}